// Round 2
// baseline (261.770 us; speedup 1.0000x reference)
//
#include <hip/hip_runtime.h>

typedef __bf16 bf16;
typedef __bf16 bf16x4 __attribute__((ext_vector_type(4)));
typedef __bf16 bf16x8 __attribute__((ext_vector_type(8)));
typedef float f32x4 __attribute__((ext_vector_type(4)));
typedef unsigned int u32x4 __attribute__((ext_vector_type(4)));

#define MFMA16 __builtin_amdgcn_mfma_f32_16x16x32_bf16

// ---------------------------------------------------------------------------
// K0: convert the four 256x256 weight matrices f32 -> bf16 (layout unchanged,
// [O][C] row-major = A-operand ready, K-contiguous).
__global__ __launch_bounds__(256) void k_cvt_w(const float* __restrict__ w0, const float* __restrict__ w1,
                                               const float* __restrict__ w2, const float* __restrict__ w3,
                                               bf16* __restrict__ dst) {
    int t = blockIdx.x * 256 + threadIdx.x;  // 65536 threads, 4 elems each
    const float* srcs[4] = {w0, w1, w2, w3};
    int which = t >> 14;                      // uniform per block (64 blocks/matrix)
    int idx = (t & 16383) * 4;
    f32x4 v = *(const f32x4*)(srcs[which] + idx);
    bf16x4 o;
    o[0] = (bf16)v[0]; o[1] = (bf16)v[1]; o[2] = (bf16)v[2]; o[3] = (bf16)v[3];
    *(bf16x4*)(dst + (size_t)which * 65536 + idx) = o;
}

// ---------------------------------------------------------------------------
// K1: transpose+convert activations: src [B][256][N] f32 -> dst rows [n][256] bf16
// (c-contiguous = B^T operand for the projection GEMMs). 64x64 tile via LDS.
__global__ __launch_bounds__(256) void k_transp(const float* __restrict__ src, bf16* __restrict__ dst,
                                                int N, int dstBatchRows, int rowOff) {
    int b = blockIdx.z;
    int c0 = blockIdx.y * 64, n0 = blockIdx.x * 64;
    __shared__ float T[64][65];
    int t = threadIdx.x;
    const float* s = src + ((size_t)b * 256 + c0) * N + n0;
#pragma unroll
    for (int i = 0; i < 4; i++) {
        int flat = i * 256 + t;
        int row = flat >> 4;          // c 0..63
        int col = (flat & 15) * 4;    // n
        f32x4 v = *(const f32x4*)(s + (size_t)row * N + col);
        T[row][col + 0] = v[0]; T[row][col + 1] = v[1];
        T[row][col + 2] = v[2]; T[row][col + 3] = v[3];
    }
    __syncthreads();
#pragma unroll
    for (int i = 0; i < 4; i++) {
        int flat = i * 256 + t;
        int nrow = flat >> 4;         // n 0..63
        int c4 = (flat & 15) * 4;     // c
        bf16x4 o;
        o[0] = (bf16)T[c4 + 0][nrow]; o[1] = (bf16)T[c4 + 1][nrow];
        o[2] = (bf16)T[c4 + 2][nrow]; o[3] = (bf16)T[c4 + 3][nrow];
        *(bf16x4*)(dst + ((size_t)(b * dstBatchRows + rowOff + n0 + nrow)) * 256 + c0 + c4) = o;
    }
}

// ---------------------------------------------------------------------------
// K2: projection GEMM  D[o][n] = sum_c W[o][c] * Xt[n][c]  (+bias)*oscale, bf16 MFMA.
// 64x64 tile / block (4 waves, wave = 16 M-rows x 64 N-cols), K staged 32/iter.
// MODE 0: store bf16 [b*8+head][n][32]        (Q and K for attention)
// MODE 1: store bf16 [b*8+head][32][Nk], kn swizzled per 128-block to match
//         k_attn's P LDS layout (col' = 8*(off&15) + (off>>4))
// MODE 2: store f32  [b][n][256]              (o-projection pre-LN)
template <int MODE>
__global__ __launch_bounds__(256) void k_proj(const bf16* __restrict__ A, const bf16* __restrict__ Bt,
                                              const float* __restrict__ bias, void* __restrict__ DstV,
                                              int Nrows, float oscale) {
    int b = blockIdx.z, m0 = blockIdx.y * 64, n0 = blockIdx.x * 64;
    __shared__ bf16 As[64 * 40];  // +8 bf16 row pad
    __shared__ bf16 Bs[64 * 40];
    int t = threadIdx.x;
    int w = t >> 6, lane = t & 63;
    int lrow = lane & 15, lk = lane >> 4;
    f32x4 acc[4] = {};
    int r = t >> 2, cc = (t & 3) * 8;
    for (int kc = 0; kc < 256; kc += 32) {
        u32x4 va = *(const u32x4*)(A + (size_t)(m0 + r) * 256 + kc + cc);
        u32x4 vb = *(const u32x4*)(Bt + ((size_t)b * Nrows + n0 + r) * 256 + kc + cc);
        *(u32x4*)(As + r * 40 + cc) = va;
        *(u32x4*)(Bs + r * 40 + cc) = vb;
        __syncthreads();
        bf16x8 af = *(const bf16x8*)(As + (w * 16 + lrow) * 40 + lk * 8);
#pragma unroll
        for (int ct = 0; ct < 4; ct++) {
            bf16x8 bfr = *(const bf16x8*)(Bs + (ct * 16 + lrow) * 40 + lk * 8);
            acc[ct] = MFMA16(af, bfr, acc[ct], 0, 0, 0);
        }
        __syncthreads();
    }
    // C/D layout: col = lane&15, row = (lane>>4)*4 + reg  [verified m89/m91]
    int o0 = m0 + w * 16 + lk * 4;
    f32x4 b4 = *(const f32x4*)(bias + o0);
#pragma unroll
    for (int ct = 0; ct < 4; ct++) {
        int n = n0 + ct * 16 + lrow;
        if (MODE == 0) {
            bf16* Dst = (bf16*)DstV;
            int head = o0 >> 5, dd = o0 & 31;
            bf16x4 pv;
#pragma unroll
            for (int i = 0; i < 4; i++) pv[i] = (bf16)((acc[ct][i] + b4[i]) * oscale);
            *(bf16x4*)(Dst + ((size_t)(b * 8 + head) * Nrows + n) * 32 + dd) = pv;
        } else if (MODE == 1) {
            bf16* Dst = (bf16*)DstV;
            int head = o0 >> 5, dd = o0 & 31;
            int off = n & 127;
            int np = (n & ~127) + 8 * (off & 15) + (off >> 4);  // kn swizzle
            size_t base = ((size_t)(b * 8 + head) * 32 + dd) * (size_t)Nrows + np;
#pragma unroll
            for (int i = 0; i < 4; i++) Dst[base + (size_t)i * Nrows] = (bf16)(acc[ct][i] + b4[i]);
        } else {
            float* Dst = (float*)DstV;
            f32x4 v;
#pragma unroll
            for (int i = 0; i < 4; i++) v[i] = acc[ct][i] + b4[i];
            *(f32x4*)(Dst + ((size_t)b * Nrows + n) * 256 + o0) = v;
        }
    }
}

// ---------------------------------------------------------------------------
// K3: attention. Q [bh][4096][32] (pre-scaled by 32^-0.5*log2e), K [bh][3072][32],
// Vt [bh][32][3072] (kn swizzled), all bf16. One wave per block, 16 q-rows,
// 128-kn iterations. Softmax without max-shift (|logit| small by construction,
// shift-invariant => exact). Row-sums via ones-B MFMA (lands in C/D rows
// exactly matching accO). P LDS layout swizzled so C/D regs pack into 4
// ds_write_b128 and A-fragments read back as ds_read_b128, both conflict-free
// at stride 136 (bank = 4*(row+lrow) mod 32 covers all banks).
__global__ __launch_bounds__(64, 3) void k_attn(const bf16* __restrict__ Q, const bf16* __restrict__ K,
                                                const bf16* __restrict__ Vt, bf16* __restrict__ aout) {
    int bh = blockIdx.y;
    int q0 = blockIdx.x * 16;
    int lane = threadIdx.x;
    int lrow = lane & 15, lk = lane >> 4;
    __shared__ bf16 P[16 * 136];
    const bf16* kbase = K + (size_t)bh * 3072 * 32;
    const bf16* vbase = Vt + (size_t)bh * 32 * 3072;
    // A-operand (Q) in registers for the whole loop: A[m=lane&15][k=(lane>>4)*8+j]
    bf16x8 aq = *(const bf16x8*)(Q + ((size_t)bh * 4096 + q0 + lrow) * 32 + lk * 8);
    bf16x8 ones;
#pragma unroll
    for (int j = 0; j < 8; j++) ones[j] = (bf16)1.0f;
    f32x4 accO0 = {}, accO1 = {}, accL = {};
    f32x4 zero = {};
    bf16* pwr = P + lrow * 8;           // write: col' base = 8*lrow
    const bf16* prd = P + lrow * 136;   // read: row q = lrow
    for (int kc = 0; kc < 3072; kc += 128) {
        bf16x8 kt[8], v0[4], v1[4];
#pragma unroll
        for (int tt = 0; tt < 8; tt++)
            kt[tt] = *(const bf16x8*)(kbase + (size_t)(kc + 16 * tt + lrow) * 32 + lk * 8);
#pragma unroll
        for (int c = 0; c < 4; c++) {
            v0[c] = *(const bf16x8*)(vbase + (size_t)lrow * 3072 + kc + 32 * c + lk * 8);
            v1[c] = *(const bf16x8*)(vbase + (size_t)(16 + lrow) * 3072 + kc + 32 * c + lk * 8);
        }
        f32x4 s[8];
#pragma unroll
        for (int tt = 0; tt < 8; tt++) s[tt] = MFMA16(aq, kt[tt], zero, 0, 0, 0);
        // S element (q=lk*4+i, col=16*tt+lrow) -> storage col' = 8*lrow + tt
#pragma unroll
        for (int i = 0; i < 4; i++) {
            bf16x8 pk;
#pragma unroll
            for (int tt = 0; tt < 8; tt++) pk[tt] = (bf16)__builtin_amdgcn_exp2f(s[tt][i]);
            *(bf16x8*)(pwr + (lk * 4 + i) * 136) = pk;
        }
        // A-read chunk c: k-slot (lk,j) = P[q][kc + 4c + lk + 16j]; V storage is
        // pre-permuted identically, so contiguous reads line up.
#pragma unroll
        for (int c = 0; c < 4; c++) {
            bf16x8 ap = *(const bf16x8*)(prd + 32 * c + lk * 8);
            accO0 = MFMA16(ap, v0[c], accO0, 0, 0, 0);
            accO1 = MFMA16(ap, v1[c], accO1, 0, 0, 0);
            accL = MFMA16(ap, ones, accL, 0, 0, 0);
        }
    }
    int b = bh >> 3, h = bh & 7;
#pragma unroll
    for (int i = 0; i < 4; i++) {
        float rl = 1.0f / accL[i];
        int q = q0 + lk * 4 + i;
        size_t rowbase = ((size_t)b * 4096 + q) * 256 + h * 32;
        aout[rowbase + lrow] = (bf16)(accO0[i] * rl);
        aout[rowbase + 16 + lrow] = (bf16)(accO1[i] * rl);
    }
}

// ---------------------------------------------------------------------------
// K4: residual + LayerNorm(C) + transpose back to [b][c][n]. Tile 32n x 256c.
__global__ __launch_bounds__(256) void k_ln(const float* __restrict__ opre, const float* __restrict__ s3,
                                            const float* __restrict__ lnw, const float* __restrict__ lnb,
                                            float* __restrict__ out) {
    int b = blockIdx.y;
    int n0 = blockIdx.x * 32;
    __shared__ float T[32][257];
    __shared__ float mu_s[32], rs_s[32];
    int t = threadIdx.x;
    // phase A: opre tile [32n][256c], coalesced along c
#pragma unroll
    for (int i = 0; i < 8; i++) {
        int flat = i * 256 + t;
        int n = flat >> 6;
        int c = (flat & 63) * 4;
        f32x4 v = *(const f32x4*)(opre + ((size_t)b * 4096 + n0 + n) * 256 + c);
        T[n][c + 0] = v[0]; T[n][c + 1] = v[1]; T[n][c + 2] = v[2]; T[n][c + 3] = v[3];
    }
    __syncthreads();
    // phase B: add residual from s3 [b][c][n], coalesced along n
#pragma unroll
    for (int i = 0; i < 8; i++) {
        int flat = i * 256 + t;
        int c = flat >> 3;
        int n = (flat & 7) * 4;
        f32x4 v = *(const f32x4*)(s3 + ((size_t)b * 256 + c) * 4096 + n0 + n);
        T[n + 0][c] += v[0]; T[n + 1][c] += v[1]; T[n + 2][c] += v[2]; T[n + 3][c] += v[3];
    }
    __syncthreads();
    // phase C: per-row mean/var (wave w handles rows w*8..w*8+7)
    int w = t >> 6, lane = t & 63;
    for (int j = 0; j < 8; j++) {
        int row = w * 8 + j;
        float x0 = T[row][lane], x1 = T[row][lane + 64];
        float x2 = T[row][lane + 128], x3 = T[row][lane + 192];
        float s = x0 + x1 + x2 + x3;
        float s2 = x0 * x0 + x1 * x1 + x2 * x2 + x3 * x3;
#pragma unroll
        for (int off = 1; off < 64; off <<= 1) {
            s += __shfl_xor(s, off, 64);
            s2 += __shfl_xor(s2, off, 64);
        }
        if (lane == 0) {
            float mu = s * (1.0f / 256.0f);
            float var = s2 * (1.0f / 256.0f) - mu * mu;
            mu_s[row] = mu;
            rs_s[row] = rsqrtf(var + 1e-5f);
        }
    }
    __syncthreads();
    // phase D: write out[b][c][n0..n0+31], each thread owns one c-row
    int c = t;
    float wv = lnw[c], bv = lnb[c];
#pragma unroll
    for (int i = 0; i < 8; i++) {
        int n = i * 4;
        f32x4 o;
#pragma unroll
        for (int k = 0; k < 4; k++)
            o[k] = (T[n + k][c] - mu_s[n + k]) * rs_s[n + k] * wv + bv;
        *(f32x4*)(out + ((size_t)b * 256 + c) * 4096 + n0 + n) = o;
    }
}

// ---------------------------------------------------------------------------
extern "C" void kernel_launch(void* const* d_in, const int* in_sizes, int n_in,
                              void* d_out, int out_size, void* d_ws, size_t ws_size,
                              hipStream_t stream) {
    const float* s3  = (const float*)d_in[0];
    const float* s4  = (const float*)d_in[1];
    const float* s5  = (const float*)d_in[2];
    const float* qw  = (const float*)d_in[3];
    const float* qb  = (const float*)d_in[4];
    const float* kw  = (const float*)d_in[5];
    const float* kb  = (const float*)d_in[6];
    const float* vw  = (const float*)d_in[7];
    const float* vb  = (const float*)d_in[8];
    const float* ow  = (const float*)d_in[9];
    const float* ob  = (const float*)d_in[10];
    const float* lnw = (const float*)d_in[11];
    const float* lnb = (const float*)d_in[12];
    float* out = (float*)d_out;
    char* ws = (char*)d_ws;

    // workspace layout (peak 17.5 MB, with dead-buffer overlays):
    bf16* s3t  = (bf16*)(ws);                                  // [2][4096][256] 4 MB
    bf16* s45t = (bf16*)(ws + (4ull << 20));                   // [2][3072][256] 3 MB
    bf16* Wb   = (bf16*)(ws + (7ull << 20));                   // 4x[256][256]  512 KB
    bf16* Qb   = (bf16*)(ws + (7ull << 20) + (512ull << 10));  // [16][4096][32] 4 MB
    bf16* Kb   = Qb + (2ull * 8 * 4096 * 32);                  // [16][3072][32] 3 MB
    bf16* Vtb  = Kb + (2ull * 8 * 3072 * 32);                  // [16][32][3072] 3 MB
    bf16* aout = s3t;            // s3t dead after Q projection
    float* opre = (float*)Qb;    // Q/K/Vt dead after attention (8 MB)

    // fold softmax scale * log2(e) into Q so k_attn uses exp2 directly
    const float qscale = 0.17677669529663688f * 1.4426950408889634f;

    k_cvt_w<<<256, 256, 0, stream>>>(qw, kw, vw, ow, Wb);
    k_transp<<<dim3(64, 4, 2), 256, 0, stream>>>(s3, s3t, 4096, 4096, 0);
    k_transp<<<dim3(32, 4, 2), 256, 0, stream>>>(s4, s45t, 2048, 3072, 0);
    k_transp<<<dim3(16, 4, 2), 256, 0, stream>>>(s5, s45t, 1024, 3072, 2048);
    k_proj<0><<<dim3(64, 4, 2), 256, 0, stream>>>(Wb,          s3t,  qb, (void*)Qb,  4096, qscale);
    k_proj<0><<<dim3(48, 4, 2), 256, 0, stream>>>(Wb + 65536,  s45t, kb, (void*)Kb,  3072, 1.0f);
    k_proj<1><<<dim3(48, 4, 2), 256, 0, stream>>>(Wb + 131072, s45t, vb, (void*)Vtb, 3072, 1.0f);
    k_attn<<<dim3(256, 16), 64, 0, stream>>>(Qb, Kb, Vtb, aout);
    k_proj<2><<<dim3(64, 4, 2), 256, 0, stream>>>(Wb + 196608, aout, ob, (void*)opre, 4096, 1.0f);
    k_ln<<<dim3(128, 2), 256, 0, stream>>>(opre, s3, lnw, lnb, out);
}

// Round 3
// 181.630 us; speedup vs baseline: 1.4412x; 1.4412x over previous
//
#include <hip/hip_runtime.h>

typedef __bf16 bf16;
typedef __bf16 bf16x4 __attribute__((ext_vector_type(4)));
typedef __bf16 bf16x8 __attribute__((ext_vector_type(8)));
typedef float f32x4 __attribute__((ext_vector_type(4)));
typedef unsigned int u32x4 __attribute__((ext_vector_type(4)));

#define MFMA16 __builtin_amdgcn_mfma_f32_16x16x32_bf16

// async 16B/lane global->LDS copy; HW scatters lane i to lds + i*16 (wave-uniform base)
__device__ __forceinline__ void async16(bf16* lds, const bf16* g) {
    __builtin_amdgcn_global_load_lds((const __attribute__((address_space(1))) unsigned int*)g,
                                     (__attribute__((address_space(3))) unsigned int*)lds, 16, 0, 0);
}

// ---------------------------------------------------------------------------
// K0: convert the four 256x256 weight matrices f32 -> bf16 (layout unchanged,
// [O][C] row-major = A-operand ready, K-contiguous).
__global__ __launch_bounds__(256) void k_cvt_w(const float* __restrict__ w0, const float* __restrict__ w1,
                                               const float* __restrict__ w2, const float* __restrict__ w3,
                                               bf16* __restrict__ dst) {
    int t = blockIdx.x * 256 + threadIdx.x;  // 65536 threads, 4 elems each
    const float* srcs[4] = {w0, w1, w2, w3};
    int which = t >> 14;                      // uniform per block (64 blocks/matrix)
    int idx = (t & 16383) * 4;
    f32x4 v = *(const f32x4*)(srcs[which] + idx);
    bf16x4 o;
    o[0] = (bf16)v[0]; o[1] = (bf16)v[1]; o[2] = (bf16)v[2]; o[3] = (bf16)v[3];
    *(bf16x4*)(dst + (size_t)which * 65536 + idx) = o;
}

// ---------------------------------------------------------------------------
// K1: transpose+convert activations: src [B][256][N] f32 -> dst rows [n][256] bf16
// (c-contiguous = B^T operand for the projection GEMMs). 64x64 tile via LDS.
__global__ __launch_bounds__(256) void k_transp(const float* __restrict__ src, bf16* __restrict__ dst,
                                                int N, int dstBatchRows, int rowOff) {
    int b = blockIdx.z;
    int c0 = blockIdx.y * 64, n0 = blockIdx.x * 64;
    __shared__ float T[64][65];
    int t = threadIdx.x;
    const float* s = src + ((size_t)b * 256 + c0) * N + n0;
#pragma unroll
    for (int i = 0; i < 4; i++) {
        int flat = i * 256 + t;
        int row = flat >> 4;          // c 0..63
        int col = (flat & 15) * 4;    // n
        f32x4 v = *(const f32x4*)(s + (size_t)row * N + col);
        T[row][col + 0] = v[0]; T[row][col + 1] = v[1];
        T[row][col + 2] = v[2]; T[row][col + 3] = v[3];
    }
    __syncthreads();
#pragma unroll
    for (int i = 0; i < 4; i++) {
        int flat = i * 256 + t;
        int nrow = flat >> 4;         // n 0..63
        int c4 = (flat & 15) * 4;     // c
        bf16x4 o;
        o[0] = (bf16)T[c4 + 0][nrow]; o[1] = (bf16)T[c4 + 1][nrow];
        o[2] = (bf16)T[c4 + 2][nrow]; o[3] = (bf16)T[c4 + 3][nrow];
        *(bf16x4*)(dst + ((size_t)(b * dstBatchRows + rowOff + n0 + nrow)) * 256 + c0 + c4) = o;
    }
}

// ---------------------------------------------------------------------------
// K2: projection GEMM  D[o][n] = sum_c W[o][c] * Xt[n][c]  (+bias)*oscale, bf16 MFMA.
// 64x64 tile / block (4 waves, wave = 16 M-rows x 64 N-cols), K staged 32/iter.
// MODE 0: store bf16 [b*8+head][n][32]        (Q and K for attention)
// MODE 1: store bf16 [b*8+head][32][Nk], kn swizzled per 64-block to match
//         k_attn's P LDS layout (np = 4*(off&15) + (off>>4), off = n&63)
// MODE 2: store f32  [b][n][256]              (o-projection pre-LN)
template <int MODE>
__global__ __launch_bounds__(256) void k_proj(const bf16* __restrict__ A, const bf16* __restrict__ Bt,
                                              const float* __restrict__ bias, void* __restrict__ DstV,
                                              int Nrows, float oscale) {
    int b = blockIdx.z, m0 = blockIdx.y * 64, n0 = blockIdx.x * 64;
    __shared__ bf16 As[64 * 40];  // +8 bf16 row pad
    __shared__ bf16 Bs[64 * 40];
    int t = threadIdx.x;
    int w = t >> 6, lane = t & 63;
    int lrow = lane & 15, lk = lane >> 4;
    f32x4 acc[4] = {};
    int r = t >> 2, cc = (t & 3) * 8;
    for (int kc = 0; kc < 256; kc += 32) {
        u32x4 va = *(const u32x4*)(A + (size_t)(m0 + r) * 256 + kc + cc);
        u32x4 vb = *(const u32x4*)(Bt + ((size_t)b * Nrows + n0 + r) * 256 + kc + cc);
        *(u32x4*)(As + r * 40 + cc) = va;
        *(u32x4*)(Bs + r * 40 + cc) = vb;
        __syncthreads();
        bf16x8 af = *(const bf16x8*)(As + (w * 16 + lrow) * 40 + lk * 8);
#pragma unroll
        for (int ct = 0; ct < 4; ct++) {
            bf16x8 bfr = *(const bf16x8*)(Bs + (ct * 16 + lrow) * 40 + lk * 8);
            acc[ct] = MFMA16(af, bfr, acc[ct], 0, 0, 0);
        }
        __syncthreads();
    }
    // C/D layout: col = lane&15, row = (lane>>4)*4 + reg  [verified m89/m91]
    int o0 = m0 + w * 16 + lk * 4;
    f32x4 b4 = *(const f32x4*)(bias + o0);
#pragma unroll
    for (int ct = 0; ct < 4; ct++) {
        int n = n0 + ct * 16 + lrow;
        if (MODE == 0) {
            bf16* Dst = (bf16*)DstV;
            int head = o0 >> 5, dd = o0 & 31;
            bf16x4 pv;
#pragma unroll
            for (int i = 0; i < 4; i++) pv[i] = (bf16)((acc[ct][i] + b4[i]) * oscale);
            *(bf16x4*)(Dst + ((size_t)(b * 8 + head) * Nrows + n) * 32 + dd) = pv;
        } else if (MODE == 1) {
            bf16* Dst = (bf16*)DstV;
            int head = o0 >> 5, dd = o0 & 31;
            int off = n & 63;
            int np = (n & ~63) + 4 * (off & 15) + (off >> 4);  // kn swizzle (64-block)
            size_t base = ((size_t)(b * 8 + head) * 32 + dd) * (size_t)Nrows + np;
#pragma unroll
            for (int i = 0; i < 4; i++) Dst[base + (size_t)i * Nrows] = (bf16)(acc[ct][i] + b4[i]);
        } else {
            float* Dst = (float*)DstV;
            f32x4 v;
#pragma unroll
            for (int i = 0; i < 4; i++) v[i] = acc[ct][i] + b4[i];
            *(f32x4*)(Dst + ((size_t)b * Nrows + n) * 256 + o0) = v;
        }
    }
}

// ---------------------------------------------------------------------------
// K3: attention, LDS-staged flash style. Q [bh][4096][32] (pre-scaled by
// 32^-0.5*log2e), K [bh][3072][32], Vt [bh][32][3072] (col-swizzled per
// 64-block), all bf16. Block = 4 waves / 64 q-rows; kn chunk = 64, K/V tiles
// async-staged into double-buffered LDS via global_load_lds (m97 pipeline:
// issue chunk c+1, compute chunk c, barrier). Softmax without max-shift
// (|logit| bounded small; shift-invariant => exact): O += exp2(S)*V,
// L += rowsum via ones-B MFMA, divide once at the end.
// Vs LDS tile cannot be padded (global_load_lds dest is uniform+lane*16), so
// bank balance comes from XOR column-block swizzle baked into staging source
// addresses; reads compensate with the same XOR.
__global__ __launch_bounds__(256, 4) void k_attn(const bf16* __restrict__ Q, const bf16* __restrict__ K,
                                                 const bf16* __restrict__ Vt, bf16* __restrict__ aout) {
    int bh = blockIdx.y;
    int q0 = blockIdx.x * 64;
    int t = threadIdx.x, w = t >> 6, lane = t & 63;
    int lrow = lane & 15, lk = lane >> 4;
    __shared__ bf16 Ks[2][64 * 32];   // [kn][d]
    __shared__ bf16 Vs[2][32 * 64];   // [d][kn-storage], xor-swizzled col blocks
    __shared__ bf16 P[4][16 * 72];    // per-wave P round-trip, padded stride 72
    const bf16* kbase = K + (size_t)bh * 3072 * 32;
    const bf16* vbase = Vt + (size_t)bh * 32 * 3072;
    // staging source pointers (lane -> LDS slot w*512 + lane*8 elems is fixed by HW)
    const bf16* kg = kbase + (size_t)(w * 16 + (lane >> 2)) * 32 + (lane & 3) * 8;
    int vr = w * 8 + (lane >> 3);                                   // Vs storage row
    const bf16* vg = vbase + (size_t)vr * 3072 + ((lane & 7) ^ (vr & 7)) * 8;
    bf16* pw = &P[w][0];
    // A-operand (Q) in registers for the whole loop: A[m=lane&15][k=(lane>>4)*8+j]
    bf16x8 aq = *(const bf16x8*)(Q + ((size_t)bh * 4096 + q0 + w * 16 + lrow) * 32 + lk * 8);
    bf16x8 ones;
#pragma unroll
    for (int j = 0; j < 8; j++) ones[j] = (bf16)1.0f;
    f32x4 accO0 = {}, accO1 = {}, accL = {};
    f32x4 zero = {};
    // prologue: stage chunk 0 into buffer 0
    async16(&Ks[0][w * 512], kg);
    async16(&Vs[0][w * 512], vg);
    __syncthreads();
    for (int c = 0; c < 48; ++c) {
        int buf = c & 1;
        if (c < 47) {
            size_t kc1 = (size_t)(c + 1) * 64;
            async16(&Ks[buf ^ 1][w * 512], kg + kc1 * 32);
            async16(&Vs[buf ^ 1][w * 512], vg + kc1);
        }
        const bf16* ksb = &Ks[buf][0];
        const bf16* vsb = &Vs[buf][0];
        // QK^T: 4 tiles of 16 kn
        f32x4 s[4];
#pragma unroll
        for (int jt = 0; jt < 4; ++jt) {
            bf16x8 bk = *(const bf16x8*)(ksb + (16 * jt + lrow) * 32 + lk * 8);
            s[jt] = MFMA16(aq, bk, zero, 0, 0, 0);
        }
        // exp2 + pack to P: element (q=4lk+i, u=16jt+lrow) -> col' = 4*lrow + jt
#pragma unroll
        for (int i = 0; i < 4; ++i) {
            bf16x4 pk;
#pragma unroll
            for (int jt = 0; jt < 4; ++jt) pk[jt] = (bf16)__builtin_amdgcn_exp2f(s[jt][i]);
            *(bf16x4*)(pw + (lk * 4 + i) * 72 + lrow * 4) = pk;
        }
        // PV: A = P[q][col'] (col'-order matches V's pre-baked global swizzle)
#pragma unroll
        for (int cs = 0; cs < 2; ++cs) {
            bf16x8 ap = *(const bf16x8*)(pw + lrow * 72 + cs * 32 + lk * 8);
            int xb = ((cs * 4 + lk) ^ (lrow & 7)) * 8;
            bf16x8 v0 = *(const bf16x8*)(vsb + lrow * 64 + xb);
            bf16x8 v1 = *(const bf16x8*)(vsb + (16 + lrow) * 64 + xb);
            accO0 = MFMA16(ap, v0, accO0, 0, 0, 0);
            accO1 = MFMA16(ap, v1, accO1, 0, 0, 0);
            accL = MFMA16(ap, ones, accL, 0, 0, 0);
        }
        __syncthreads();
    }
    int b = bh >> 3, h = bh & 7;
#pragma unroll
    for (int i = 0; i < 4; i++) {
        float rl = 1.0f / accL[i];
        int q = q0 + w * 16 + lk * 4 + i;
        size_t rowbase = ((size_t)b * 4096 + q) * 256 + h * 32;
        aout[rowbase + lrow] = (bf16)(accO0[i] * rl);
        aout[rowbase + 16 + lrow] = (bf16)(accO1[i] * rl);
    }
}

// ---------------------------------------------------------------------------
// K4: residual + LayerNorm(C) + transpose back to [b][c][n]. Tile 32n x 256c.
__global__ __launch_bounds__(256) void k_ln(const float* __restrict__ opre, const float* __restrict__ s3,
                                            const float* __restrict__ lnw, const float* __restrict__ lnb,
                                            float* __restrict__ out) {
    int b = blockIdx.y;
    int n0 = blockIdx.x * 32;
    __shared__ float T[32][257];
    __shared__ float mu_s[32], rs_s[32];
    int t = threadIdx.x;
    // phase A: opre tile [32n][256c], coalesced along c
#pragma unroll
    for (int i = 0; i < 8; i++) {
        int flat = i * 256 + t;
        int n = flat >> 6;
        int c = (flat & 63) * 4;
        f32x4 v = *(const f32x4*)(opre + ((size_t)b * 4096 + n0 + n) * 256 + c);
        T[n][c + 0] = v[0]; T[n][c + 1] = v[1]; T[n][c + 2] = v[2]; T[n][c + 3] = v[3];
    }
    __syncthreads();
    // phase B: add residual from s3 [b][c][n], coalesced along n
#pragma unroll
    for (int i = 0; i < 8; i++) {
        int flat = i * 256 + t;
        int c = flat >> 3;
        int n = (flat & 7) * 4;
        f32x4 v = *(const f32x4*)(s3 + ((size_t)b * 256 + c) * 4096 + n0 + n);
        T[n + 0][c] += v[0]; T[n + 1][c] += v[1]; T[n + 2][c] += v[2]; T[n + 3][c] += v[3];
    }
    __syncthreads();
    // phase C: per-row mean/var (wave w handles rows w*8..w*8+7)
    int w = t >> 6, lane = t & 63;
    for (int j = 0; j < 8; j++) {
        int row = w * 8 + j;
        float x0 = T[row][lane], x1 = T[row][lane + 64];
        float x2 = T[row][lane + 128], x3 = T[row][lane + 192];
        float s = x0 + x1 + x2 + x3;
        float s2 = x0 * x0 + x1 * x1 + x2 * x2 + x3 * x3;
#pragma unroll
        for (int off = 1; off < 64; off <<= 1) {
            s += __shfl_xor(s, off, 64);
            s2 += __shfl_xor(s2, off, 64);
        }
        if (lane == 0) {
            float mu = s * (1.0f / 256.0f);
            float var = s2 * (1.0f / 256.0f) - mu * mu;
            mu_s[row] = mu;
            rs_s[row] = rsqrtf(var + 1e-5f);
        }
    }
    __syncthreads();
    // phase D: write out[b][c][n0..n0+31], each thread owns one c-row
    int c = t;
    float wv = lnw[c], bv = lnb[c];
#pragma unroll
    for (int i = 0; i < 8; i++) {
        int n = i * 4;
        f32x4 o;
#pragma unroll
        for (int k = 0; k < 4; k++)
            o[k] = (T[n + k][c] - mu_s[n + k]) * rs_s[n + k] * wv + bv;
        *(f32x4*)(out + ((size_t)b * 256 + c) * 4096 + n0 + n) = o;
    }
}

// ---------------------------------------------------------------------------
extern "C" void kernel_launch(void* const* d_in, const int* in_sizes, int n_in,
                              void* d_out, int out_size, void* d_ws, size_t ws_size,
                              hipStream_t stream) {
    const float* s3  = (const float*)d_in[0];
    const float* s4  = (const float*)d_in[1];
    const float* s5  = (const float*)d_in[2];
    const float* qw  = (const float*)d_in[3];
    const float* qb  = (const float*)d_in[4];
    const float* kw  = (const float*)d_in[5];
    const float* kb  = (const float*)d_in[6];
    const float* vw  = (const float*)d_in[7];
    const float* vb  = (const float*)d_in[8];
    const float* ow  = (const float*)d_in[9];
    const float* ob  = (const float*)d_in[10];
    const float* lnw = (const float*)d_in[11];
    const float* lnb = (const float*)d_in[12];
    float* out = (float*)d_out;
    char* ws = (char*)d_ws;

    // workspace layout (peak 17.5 MB, with dead-buffer overlays):
    bf16* s3t  = (bf16*)(ws);                                  // [2][4096][256] 4 MB
    bf16* s45t = (bf16*)(ws + (4ull << 20));                   // [2][3072][256] 3 MB
    bf16* Wb   = (bf16*)(ws + (7ull << 20));                   // 4x[256][256]  512 KB
    bf16* Qb   = (bf16*)(ws + (7ull << 20) + (512ull << 10));  // [16][4096][32] 4 MB
    bf16* Kb   = Qb + (2ull * 8 * 4096 * 32);                  // [16][3072][32] 3 MB
    bf16* Vtb  = Kb + (2ull * 8 * 3072 * 32);                  // [16][32][3072] 3 MB
    bf16* aout = s3t;            // s3t dead after Q projection
    float* opre = (float*)Qb;    // Q/K/Vt dead after attention (8 MB)

    // fold softmax scale * log2(e) into Q so k_attn uses exp2 directly
    const float qscale = 0.17677669529663688f * 1.4426950408889634f;

    k_cvt_w<<<256, 256, 0, stream>>>(qw, kw, vw, ow, Wb);
    k_transp<<<dim3(64, 4, 2), 256, 0, stream>>>(s3, s3t, 4096, 4096, 0);
    k_transp<<<dim3(32, 4, 2), 256, 0, stream>>>(s4, s45t, 2048, 3072, 0);
    k_transp<<<dim3(16, 4, 2), 256, 0, stream>>>(s5, s45t, 1024, 3072, 2048);
    k_proj<0><<<dim3(64, 4, 2), 256, 0, stream>>>(Wb,          s3t,  qb, (void*)Qb,  4096, qscale);
    k_proj<0><<<dim3(48, 4, 2), 256, 0, stream>>>(Wb + 65536,  s45t, kb, (void*)Kb,  3072, 1.0f);
    k_proj<1><<<dim3(48, 4, 2), 256, 0, stream>>>(Wb + 131072, s45t, vb, (void*)Vtb, 3072, 1.0f);
    k_attn<<<dim3(64, 16), 256, 0, stream>>>(Qb, Kb, Vtb, aout);
    k_proj<2><<<dim3(64, 4, 2), 256, 0, stream>>>(Wb + 196608, aout, ob, (void*)opre, 4096, 1.0f);
    k_ln<<<dim3(128, 2), 256, 0, stream>>>(opre, s3, lnw, lnb, out);
}

// Round 4
// 167.806 us; speedup vs baseline: 1.5600x; 1.0824x over previous
//
#include <hip/hip_runtime.h>

typedef __bf16 bf16;
typedef __bf16 bf16x4 __attribute__((ext_vector_type(4)));
typedef __bf16 bf16x8 __attribute__((ext_vector_type(8)));
typedef float f32x4 __attribute__((ext_vector_type(4)));
typedef unsigned int u32x4 __attribute__((ext_vector_type(4)));

#define MFMA16 __builtin_amdgcn_mfma_f32_16x16x32_bf16

// async 16B/lane global->LDS copy; HW scatters lane i to lds + i*16 (wave-uniform base)
__device__ __forceinline__ void async16(bf16* lds, const bf16* g) {
    __builtin_amdgcn_global_load_lds((const __attribute__((address_space(1))) unsigned int*)g,
                                     (__attribute__((address_space(3))) unsigned int*)lds, 16, 0, 0);
}

// ---------------------------------------------------------------------------
// K0 "prep": one launch does weight cvt (blocks 0..255) + the three activation
// transposes (s3: 256..767, s4: 768..1023, s5: 1024..1151). All roles are
// block-uniform branches; concurrent blocks fill the GPU far better than 4
// sequential small launches.
__global__ __launch_bounds__(256) void k_prep(const float* __restrict__ qw, const float* __restrict__ kw,
                                              const float* __restrict__ vw, const float* __restrict__ ow,
                                              bf16* __restrict__ Wb,
                                              const float* __restrict__ s3, const float* __restrict__ s4,
                                              const float* __restrict__ s5,
                                              bf16* __restrict__ s3t, bf16* __restrict__ s45t) {
    __shared__ float T[64][65];
    int bx = blockIdx.x, t = threadIdx.x;
    if (bx < 256) {  // weight cvt: 4 x 256x256 f32 -> bf16, layout unchanged
        int tt = bx * 256 + t;
        const float* srcs[4] = {qw, kw, vw, ow};
        int which = tt >> 14;
        int idx = (tt & 16383) * 4;
        f32x4 v = *(const f32x4*)(srcs[which] + idx);
        bf16x4 o;
        o[0] = (bf16)v[0]; o[1] = (bf16)v[1]; o[2] = (bf16)v[2]; o[3] = (bf16)v[3];
        *(bf16x4*)(Wb + (size_t)which * 65536 + idx) = o;
        return;
    }
    const float* src; bf16* dst; int N, dstRows, rowOff, x, y, z;
    if (bx < 768)       { int i = bx - 256;  src = s3; dst = s3t;  N = 4096; dstRows = 4096; rowOff = 0;    x = i & 63; y = (i >> 6) & 3; z = i >> 8; }
    else if (bx < 1024) { int i = bx - 768;  src = s4; dst = s45t; N = 2048; dstRows = 3072; rowOff = 0;    x = i & 31; y = (i >> 5) & 3; z = i >> 7; }
    else                { int i = bx - 1024; src = s5; dst = s45t; N = 1024; dstRows = 3072; rowOff = 2048; x = i & 15; y = (i >> 4) & 3; z = i >> 6; }
    int c0 = y * 64, n0 = x * 64, b = z;
    const float* s = src + ((size_t)b * 256 + c0) * N + n0;
#pragma unroll
    for (int i = 0; i < 4; i++) {
        int flat = i * 256 + t;
        int row = flat >> 4;          // c 0..63
        int col = (flat & 15) * 4;    // n
        f32x4 v = *(const f32x4*)(s + (size_t)row * N + col);
        T[row][col + 0] = v[0]; T[row][col + 1] = v[1];
        T[row][col + 2] = v[2]; T[row][col + 3] = v[3];
    }
    __syncthreads();
#pragma unroll
    for (int i = 0; i < 4; i++) {
        int flat = i * 256 + t;
        int nrow = flat >> 4;         // n 0..63
        int c4 = (flat & 15) * 4;     // c
        bf16x4 o;
        o[0] = (bf16)T[c4 + 0][nrow]; o[1] = (bf16)T[c4 + 1][nrow];
        o[2] = (bf16)T[c4 + 2][nrow]; o[3] = (bf16)T[c4 + 3][nrow];
        *(bf16x4*)(dst + ((size_t)(b * dstRows + rowOff + n0 + nrow)) * 256 + c0 + c4) = o;
    }
}

// ---------------------------------------------------------------------------
// K1 "qkv": all three input projections in one launch (blocks: Q 0..511,
// K 512..895, V 896..1279).  D[o][n] = sum_c W[o][c] * Xt[n][c] (+bias)*oscale.
// mode 0: bf16 [b*8+head][n][32]  (Q pre-scaled by 32^-.5*log2e; K plain)
// mode 1: bf16 [b*8+head][32][Nk], kn swizzled per 64-block to match k_attn's
//         P LDS layout (np = 4*(off&15) + (off>>4), off = n&63)
__global__ __launch_bounds__(256) void k_qkv(const bf16* __restrict__ Wb,
                                             const bf16* __restrict__ s3t, const bf16* __restrict__ s45t,
                                             const float* __restrict__ qb, const float* __restrict__ kb,
                                             const float* __restrict__ vb,
                                             bf16* __restrict__ Qb, bf16* __restrict__ Kb,
                                             bf16* __restrict__ Vtb, float qscale) {
    int i = blockIdx.x;
    int mode, n0, m0, b, Nrows;
    const bf16 *A, *Bt; const float* bias; bf16* Dst; float oscale = 1.0f;
    if (i < 512) {
        mode = 0; A = Wb; Bt = s3t; bias = qb; Dst = Qb; Nrows = 4096; oscale = qscale;
        n0 = (i & 63) * 64; m0 = ((i >> 6) & 3) * 64; b = i >> 8;
    } else if (i < 896) {
        unsigned j = i - 512;
        mode = 0; A = Wb + 65536; Bt = s45t; bias = kb; Dst = Kb; Nrows = 3072;
        n0 = (j % 48u) * 64; unsigned rr = j / 48u; m0 = (rr & 3) * 64; b = rr >> 2;
    } else {
        unsigned j = i - 896;
        mode = 1; A = Wb + 131072; Bt = s45t; bias = vb; Dst = Vtb; Nrows = 3072;
        n0 = (j % 48u) * 64; unsigned rr = j / 48u; m0 = (rr & 3) * 64; b = rr >> 2;
    }
    __shared__ bf16 As[64 * 40];  // +8 bf16 row pad
    __shared__ bf16 Bs[64 * 40];
    int t = threadIdx.x;
    int w = t >> 6, lane = t & 63;
    int lrow = lane & 15, lk = lane >> 4;
    f32x4 acc[4] = {};
    int r = t >> 2, cc = (t & 3) * 8;
    for (int kc = 0; kc < 256; kc += 32) {
        u32x4 va = *(const u32x4*)(A + (size_t)(m0 + r) * 256 + kc + cc);
        u32x4 vbv = *(const u32x4*)(Bt + ((size_t)b * Nrows + n0 + r) * 256 + kc + cc);
        *(u32x4*)(As + r * 40 + cc) = va;
        *(u32x4*)(Bs + r * 40 + cc) = vbv;
        __syncthreads();
        bf16x8 af = *(const bf16x8*)(As + (w * 16 + lrow) * 40 + lk * 8);
#pragma unroll
        for (int ct = 0; ct < 4; ct++) {
            bf16x8 bfr = *(const bf16x8*)(Bs + (ct * 16 + lrow) * 40 + lk * 8);
            acc[ct] = MFMA16(af, bfr, acc[ct], 0, 0, 0);
        }
        __syncthreads();
    }
    // C/D layout: col = lane&15, row = (lane>>4)*4 + reg  [verified m89/m91]
    int o0 = m0 + w * 16 + lk * 4;
    f32x4 b4 = *(const f32x4*)(bias + o0);
    int head = o0 >> 5, dd = o0 & 31;
#pragma unroll
    for (int ct = 0; ct < 4; ct++) {
        int n = n0 + ct * 16 + lrow;
        if (mode == 0) {
            bf16x4 pv;
#pragma unroll
            for (int j = 0; j < 4; j++) pv[j] = (bf16)((acc[ct][j] + b4[j]) * oscale);
            *(bf16x4*)(Dst + ((size_t)(b * 8 + head) * Nrows + n) * 32 + dd) = pv;
        } else {
            int off = n & 63;
            int np = (n & ~63) + 4 * (off & 15) + (off >> 4);  // kn swizzle (64-block)
            size_t base = ((size_t)(b * 8 + head) * 32 + dd) * (size_t)Nrows + np;
#pragma unroll
            for (int j = 0; j < 4; j++) Dst[base + (size_t)j * Nrows] = (bf16)(acc[ct][j] + b4[j]);
        }
    }
}

// ---------------------------------------------------------------------------
// K2: attention, split-kn=2 for occupancy (accO/accL are pure sums under
// no-max softmax, so kn halves combine as (O1+O2)/(L1+L2) — done later in
// k_oproj's staging for free). Q [bh][4096][32] (pre-scaled), K [bh][3072][32],
// Vt [bh][32][3072] (col-swizzled per 64-block), all bf16. Block = 4 waves /
// 64 q / 1536 kn; chunk = 64, K/V async-staged into dbuf LDS (m97 pipeline).
// Partial O (f32 [2*16][4096][32]) and L (f32 [2*16][4096]) to workspace.
// LDS 25.2 KB -> 6 blocks/CU; grid 2048 -> ~24 waves/CU.
__global__ __launch_bounds__(256, 6) void k_attn(const bf16* __restrict__ Q, const bf16* __restrict__ K,
                                                 const bf16* __restrict__ Vt,
                                                 float* __restrict__ Opart, float* __restrict__ Lsum) {
    int bh = blockIdx.y;
    int q0 = blockIdx.x * 64;
    int sp = blockIdx.z;             // kn split half
    int kn0 = sp * 1536;
    int t = threadIdx.x, w = t >> 6, lane = t & 63;
    int lrow = lane & 15, lk = lane >> 4;
    __shared__ bf16 Ks[2][64 * 32];   // [kn][d]
    __shared__ bf16 Vs[2][32 * 64];   // [d][kn-storage], xor-swizzled col blocks
    __shared__ bf16 P[4][16 * 72];    // per-wave P round-trip, padded stride 72
    const bf16* kbase = K + (size_t)bh * 3072 * 32;
    const bf16* vbase = Vt + (size_t)bh * 32 * 3072;
    // staging source pointers (lane -> LDS slot w*512 + lane*8 elems is fixed by HW)
    const bf16* kg = kbase + (size_t)(kn0 + w * 16 + (lane >> 2)) * 32 + (lane & 3) * 8;
    int vr = w * 8 + (lane >> 3);                                   // Vs storage row
    const bf16* vg = vbase + (size_t)vr * 3072 + kn0 + ((lane & 7) ^ (vr & 7)) * 8;
    bf16* pw = &P[w][0];
    // A-operand (Q) in registers for the whole loop: A[m=lane&15][k=(lane>>4)*8+j]
    bf16x8 aq = *(const bf16x8*)(Q + ((size_t)bh * 4096 + q0 + w * 16 + lrow) * 32 + lk * 8);
    bf16x8 ones;
#pragma unroll
    for (int j = 0; j < 8; j++) ones[j] = (bf16)1.0f;
    f32x4 accO0 = {}, accO1 = {}, accL = {};
    f32x4 zero = {};
    // prologue: stage chunk 0 into buffer 0
    async16(&Ks[0][w * 512], kg);
    async16(&Vs[0][w * 512], vg);
    __syncthreads();
    for (int c = 0; c < 24; ++c) {
        int buf = c & 1;
        if (c < 23) {
            size_t kc1 = (size_t)(c + 1) * 64;
            async16(&Ks[buf ^ 1][w * 512], kg + kc1 * 32);
            async16(&Vs[buf ^ 1][w * 512], vg + kc1);
        }
        const bf16* ksb = &Ks[buf][0];
        const bf16* vsb = &Vs[buf][0];
        // QK^T: 4 tiles of 16 kn
        f32x4 s[4];
#pragma unroll
        for (int jt = 0; jt < 4; ++jt) {
            bf16x8 bk = *(const bf16x8*)(ksb + (16 * jt + lrow) * 32 + lk * 8);
            s[jt] = MFMA16(aq, bk, zero, 0, 0, 0);
        }
        // exp2 + pack to P: element (q=4lk+i, u=16jt+lrow) -> col' = 4*lrow + jt
#pragma unroll
        for (int i = 0; i < 4; ++i) {
            bf16x4 pk;
#pragma unroll
            for (int jt = 0; jt < 4; ++jt) pk[jt] = (bf16)__builtin_amdgcn_exp2f(s[jt][i]);
            *(bf16x4*)(pw + (lk * 4 + i) * 72 + lrow * 4) = pk;
        }
        // PV: A = P[q][col'] (col'-order matches V's pre-baked global swizzle)
#pragma unroll
        for (int cs = 0; cs < 2; ++cs) {
            bf16x8 ap = *(const bf16x8*)(pw + lrow * 72 + cs * 32 + lk * 8);
            int xb = ((cs * 4 + lk) ^ (lrow & 7)) * 8;
            bf16x8 v0 = *(const bf16x8*)(vsb + lrow * 64 + xb);
            bf16x8 v1 = *(const bf16x8*)(vsb + (16 + lrow) * 64 + xb);
            accO0 = MFMA16(ap, v0, accO0, 0, 0, 0);
            accO1 = MFMA16(ap, v1, accO1, 0, 0, 0);
            accL = MFMA16(ap, ones, accL, 0, 0, 0);
        }
        __syncthreads();
    }
    float* Op = Opart + (size_t)(sp * 16 + bh) * 4096 * 32;
#pragma unroll
    for (int i = 0; i < 4; i++) {
        int q = q0 + w * 16 + lk * 4 + i;
        Op[(size_t)q * 32 + lrow] = accO0[i];
        Op[(size_t)q * 32 + 16 + lrow] = accO1[i];
        if (lrow == 0) Lsum[(size_t)(sp * 16 + bh) * 4096 + q] = accL[i];
    }
}

// ---------------------------------------------------------------------------
// K3: o-projection with fused split-kn combine in the B-staging:
// B^T[n][c = h*32+dd] = (O1+O2)*1/(L1+L2), converted to bf16 on the fly.
// Each K-step (32 channels) is exactly one head. Output f32 opre[b][n][256].
__global__ __launch_bounds__(256) void k_oproj(const bf16* __restrict__ A, const float* __restrict__ Opart,
                                               const float* __restrict__ Ls, const float* __restrict__ bias,
                                               float* __restrict__ opre) {
    int i = blockIdx.x;
    int n0 = (i & 63) * 64, m0 = ((i >> 6) & 3) * 64, b = i >> 8;
    __shared__ bf16 As[64 * 40];
    __shared__ bf16 Bs[64 * 40];
    int t = threadIdx.x;
    int w = t >> 6, lane = t & 63;
    int lrow = lane & 15, lk = lane >> 4;
    f32x4 acc[4] = {};
    int r = t >> 2, cc = (t & 3) * 8;
    int q = n0 + r;
    for (int kc = 0; kc < 256; kc += 32) {
        int h = kc >> 5, bh = b * 8 + h;
        u32x4 va = *(const u32x4*)(A + (size_t)(m0 + r) * 256 + kc + cc);
        const float* o1 = Opart + ((size_t)bh * 4096 + q) * 32 + cc;
        const float* o2 = Opart + ((size_t)(16 + bh) * 4096 + q) * 32 + cc;
        f32x4 p0 = *(const f32x4*)o1, p1 = *(const f32x4*)(o1 + 4);
        f32x4 r0 = *(const f32x4*)o2, r1 = *(const f32x4*)(o2 + 4);
        float l = Ls[(size_t)bh * 4096 + q] + Ls[(size_t)(16 + bh) * 4096 + q];
        float rl = 1.0f / l;
        bf16x8 bb;
#pragma unroll
        for (int j = 0; j < 4; j++) {
            bb[j] = (bf16)((p0[j] + r0[j]) * rl);
            bb[4 + j] = (bf16)((p1[j] + r1[j]) * rl);
        }
        *(u32x4*)(As + r * 40 + cc) = va;
        *(bf16x8*)(Bs + r * 40 + cc) = bb;
        __syncthreads();
        bf16x8 af = *(const bf16x8*)(As + (w * 16 + lrow) * 40 + lk * 8);
#pragma unroll
        for (int ct = 0; ct < 4; ct++) {
            bf16x8 bfr = *(const bf16x8*)(Bs + (ct * 16 + lrow) * 40 + lk * 8);
            acc[ct] = MFMA16(af, bfr, acc[ct], 0, 0, 0);
        }
        __syncthreads();
    }
    int o0 = m0 + w * 16 + lk * 4;
    f32x4 b4 = *(const f32x4*)(bias + o0);
#pragma unroll
    for (int ct = 0; ct < 4; ct++) {
        int n = n0 + ct * 16 + lrow;
        f32x4 v;
#pragma unroll
        for (int j = 0; j < 4; j++) v[j] = acc[ct][j] + b4[j];
        *(f32x4*)(opre + ((size_t)b * 4096 + n) * 256 + o0) = v;
    }
}

// ---------------------------------------------------------------------------
// K4: residual + LayerNorm(C) + transpose back to [b][c][n]. Tile 32n x 256c.
__global__ __launch_bounds__(256) void k_ln(const float* __restrict__ opre, const float* __restrict__ s3,
                                            const float* __restrict__ lnw, const float* __restrict__ lnb,
                                            float* __restrict__ out) {
    int b = blockIdx.y;
    int n0 = blockIdx.x * 32;
    __shared__ float T[32][257];
    __shared__ float mu_s[32], rs_s[32];
    int t = threadIdx.x;
#pragma unroll
    for (int i = 0; i < 8; i++) {
        int flat = i * 256 + t;
        int n = flat >> 6;
        int c = (flat & 63) * 4;
        f32x4 v = *(const f32x4*)(opre + ((size_t)b * 4096 + n0 + n) * 256 + c);
        T[n][c + 0] = v[0]; T[n][c + 1] = v[1]; T[n][c + 2] = v[2]; T[n][c + 3] = v[3];
    }
    __syncthreads();
#pragma unroll
    for (int i = 0; i < 8; i++) {
        int flat = i * 256 + t;
        int c = flat >> 3;
        int n = (flat & 7) * 4;
        f32x4 v = *(const f32x4*)(s3 + ((size_t)b * 256 + c) * 4096 + n0 + n);
        T[n + 0][c] += v[0]; T[n + 1][c] += v[1]; T[n + 2][c] += v[2]; T[n + 3][c] += v[3];
    }
    __syncthreads();
    int w = t >> 6, lane = t & 63;
    for (int j = 0; j < 8; j++) {
        int row = w * 8 + j;
        float x0 = T[row][lane], x1 = T[row][lane + 64];
        float x2 = T[row][lane + 128], x3 = T[row][lane + 192];
        float s = x0 + x1 + x2 + x3;
        float s2 = x0 * x0 + x1 * x1 + x2 * x2 + x3 * x3;
#pragma unroll
        for (int off = 1; off < 64; off <<= 1) {
            s += __shfl_xor(s, off, 64);
            s2 += __shfl_xor(s2, off, 64);
        }
        if (lane == 0) {
            float mu = s * (1.0f / 256.0f);
            float var = s2 * (1.0f / 256.0f) - mu * mu;
            mu_s[row] = mu;
            rs_s[row] = rsqrtf(var + 1e-5f);
        }
    }
    __syncthreads();
    int c = t;
    float wv = lnw[c], bv = lnb[c];
#pragma unroll
    for (int i = 0; i < 8; i++) {
        int n = i * 4;
        f32x4 o;
#pragma unroll
        for (int k = 0; k < 4; k++)
            o[k] = (T[n + k][c] - mu_s[n + k]) * rs_s[n + k] * wv + bv;
        *(f32x4*)(out + ((size_t)b * 256 + c) * 4096 + n0 + n) = o;
    }
}

// ---------------------------------------------------------------------------
extern "C" void kernel_launch(void* const* d_in, const int* in_sizes, int n_in,
                              void* d_out, int out_size, void* d_ws, size_t ws_size,
                              hipStream_t stream) {
    const float* s3  = (const float*)d_in[0];
    const float* s4  = (const float*)d_in[1];
    const float* s5  = (const float*)d_in[2];
    const float* qw  = (const float*)d_in[3];
    const float* qb  = (const float*)d_in[4];
    const float* kw  = (const float*)d_in[5];
    const float* kb  = (const float*)d_in[6];
    const float* vw  = (const float*)d_in[7];
    const float* vb  = (const float*)d_in[8];
    const float* ow  = (const float*)d_in[9];
    const float* ob  = (const float*)d_in[10];
    const float* lnw = (const float*)d_in[11];
    const float* lnb = (const float*)d_in[12];
    float* out = (float*)d_out;
    char* ws = (char*)d_ws;

    // workspace layout (34 MB peak, with dead-buffer overlays):
    bf16* Wb    = (bf16*)(ws);                          // 512 KB @ 0
    bf16* s3t   = (bf16*)(ws + (512ull << 10));         // 4 MB  @ 0.5 MB
    bf16* s45t  = (bf16*)(ws + (4608ull << 10));        // 3 MB  @ 4.5 MB
    bf16* Qb    = (bf16*)(ws + (7680ull << 10));        // 4 MB  @ 7.5 MB
    bf16* Kb    = Qb + (2ull * 8 * 4096 * 32);          // 3 MB  @ 11.5 MB
    bf16* Vtb   = Kb + (2ull * 8 * 3072 * 32);          // 3 MB  @ 14.5 MB
    float* Opart = (float*)(ws + (17920ull << 10));     // 16 MB @ 17.5 MB
    float* Lsum  = (float*)(ws + (34304ull << 10));     // 512 KB @ 33.5 MB
    float* opre  = (float*)(ws + (512ull << 10));       // 8 MB @ 0.5 (over s3t/s45t/Qb head, dead post-attn)

    // fold softmax scale * log2(e) into Q so k_attn uses exp2 directly
    const float qscale = 0.17677669529663688f * 1.4426950408889634f;

    k_prep<<<1152, 256, 0, stream>>>(qw, kw, vw, ow, Wb, s3, s4, s5, s3t, s45t);
    k_qkv<<<1280, 256, 0, stream>>>(Wb, s3t, s45t, qb, kb, vb, Qb, Kb, Vtb, qscale);
    k_attn<<<dim3(64, 16, 2), 256, 0, stream>>>(Qb, Kb, Vtb, Opart, Lsum);
    k_oproj<<<512, 256, 0, stream>>>(Wb + 196608, Opart, Lsum, ob, opre);
    k_ln<<<dim3(128, 2), 256, 0, stream>>>(opre, s3, lnw, lnb, out);
}

// Round 5
// 161.864 us; speedup vs baseline: 1.6172x; 1.0367x over previous
//
#include <hip/hip_runtime.h>

typedef __bf16 bf16;
typedef __bf16 bf16x4 __attribute__((ext_vector_type(4)));
typedef __bf16 bf16x8 __attribute__((ext_vector_type(8)));
typedef _Float16 f16;
typedef _Float16 f16x4 __attribute__((ext_vector_type(4)));
typedef float f32x4 __attribute__((ext_vector_type(4)));
typedef unsigned int u32x4 __attribute__((ext_vector_type(4)));

#define MFMA16 __builtin_amdgcn_mfma_f32_16x16x32_bf16
#define MFMA16F __builtin_amdgcn_mfma_f32_16x16x16f16

// async 16B/lane global->LDS copy; HW scatters lane i to lds + i*16 (wave-uniform base)
__device__ __forceinline__ void async16(void* lds, const void* g) {
    __builtin_amdgcn_global_load_lds((const __attribute__((address_space(1))) unsigned int*)g,
                                     (__attribute__((address_space(3))) unsigned int*)lds, 16, 0, 0);
}

// ---------------------------------------------------------------------------
// K0 "prep": one launch does weight cvt (blocks 0..255) + the three activation
// transposes (s3: 256..767, s4: 768..1023, s5: 1024..1151).
__global__ __launch_bounds__(256) void k_prep(const float* __restrict__ qw, const float* __restrict__ kw,
                                              const float* __restrict__ vw, const float* __restrict__ ow,
                                              bf16* __restrict__ Wb,
                                              const float* __restrict__ s3, const float* __restrict__ s4,
                                              const float* __restrict__ s5,
                                              bf16* __restrict__ s3t, bf16* __restrict__ s45t) {
    __shared__ float T[64][65];
    int bx = blockIdx.x, t = threadIdx.x;
    if (bx < 256) {  // weight cvt: 4 x 256x256 f32 -> bf16, layout unchanged
        int tt = bx * 256 + t;
        const float* srcs[4] = {qw, kw, vw, ow};
        int which = tt >> 14;
        int idx = (tt & 16383) * 4;
        f32x4 v = *(const f32x4*)(srcs[which] + idx);
        bf16x4 o;
        o[0] = (bf16)v[0]; o[1] = (bf16)v[1]; o[2] = (bf16)v[2]; o[3] = (bf16)v[3];
        *(bf16x4*)(Wb + (size_t)which * 65536 + idx) = o;
        return;
    }
    const float* src; bf16* dst; int N, dstRows, rowOff, x, y, z;
    if (bx < 768)       { int i = bx - 256;  src = s3; dst = s3t;  N = 4096; dstRows = 4096; rowOff = 0;    x = i & 63; y = (i >> 6) & 3; z = i >> 8; }
    else if (bx < 1024) { int i = bx - 768;  src = s4; dst = s45t; N = 2048; dstRows = 3072; rowOff = 0;    x = i & 31; y = (i >> 5) & 3; z = i >> 7; }
    else                { int i = bx - 1024; src = s5; dst = s45t; N = 1024; dstRows = 3072; rowOff = 2048; x = i & 15; y = (i >> 4) & 3; z = i >> 6; }
    int c0 = y * 64, n0 = x * 64, b = z;
    const float* s = src + ((size_t)b * 256 + c0) * N + n0;
#pragma unroll
    for (int i = 0; i < 4; i++) {
        int flat = i * 256 + t;
        int row = flat >> 4;          // c 0..63
        int col = (flat & 15) * 4;    // n
        f32x4 v = *(const f32x4*)(s + (size_t)row * N + col);
        T[row][col + 0] = v[0]; T[row][col + 1] = v[1];
        T[row][col + 2] = v[2]; T[row][col + 3] = v[3];
    }
    __syncthreads();
#pragma unroll
    for (int i = 0; i < 4; i++) {
        int flat = i * 256 + t;
        int nrow = flat >> 4;         // n 0..63
        int c4 = (flat & 15) * 4;     // c
        bf16x4 o;
        o[0] = (bf16)T[c4 + 0][nrow]; o[1] = (bf16)T[c4 + 1][nrow];
        o[2] = (bf16)T[c4 + 2][nrow]; o[3] = (bf16)T[c4 + 3][nrow];
        *(bf16x4*)(dst + ((size_t)(b * dstRows + rowOff + n0 + nrow)) * 256 + c0 + c4) = o;
    }
}

// ---------------------------------------------------------------------------
// K1 "qkv": all three input projections in one launch (blocks: Q 0..511,
// K 512..895, V 896..1279).
// mode 0: bf16 [b*8+head][n][32]  (Q pre-scaled by 32^-.5*log2e; K plain)
// mode 1: f16  [b*8+head][32 d][3072 kn], kn permuted within each 64-chunk by
//         a d-keyed XOR on 4-elem granules: col = (n&~63) + ((g^kk)<<2)+(n&3),
//         g=(n&63)>>2, kk=((d&7)<<1)|((d>>3)&1). This is the exact LDS image
//         k_attn's V A-frag reads expect (bank-optimal b64 reads).
__global__ __launch_bounds__(256) void k_qkv(const bf16* __restrict__ Wb,
                                             const bf16* __restrict__ s3t, const bf16* __restrict__ s45t,
                                             const float* __restrict__ qb, const float* __restrict__ kb,
                                             const float* __restrict__ vb,
                                             bf16* __restrict__ Qb, bf16* __restrict__ Kb,
                                             f16* __restrict__ Vtb, float qscale) {
    int i = blockIdx.x;
    int mode, n0, m0, b, Nrows;
    const bf16 *A, *Bt; const float* bias; float oscale = 1.0f;
    if (i < 512) {
        mode = 0; A = Wb; Bt = s3t; bias = qb; Nrows = 4096; oscale = qscale;
        n0 = (i & 63) * 64; m0 = ((i >> 6) & 3) * 64; b = i >> 8;
    } else if (i < 896) {
        unsigned j = i - 512;
        mode = 0; A = Wb + 65536; Bt = s45t; bias = kb; Nrows = 3072;
        n0 = (j % 48u) * 64; unsigned rr = j / 48u; m0 = (rr & 3) * 64; b = rr >> 2;
    } else {
        unsigned j = i - 896;
        mode = 1; A = Wb + 131072; Bt = s45t; bias = vb; Nrows = 3072;
        n0 = (j % 48u) * 64; unsigned rr = j / 48u; m0 = (rr & 3) * 64; b = rr >> 2;
    }
    __shared__ bf16 As[64 * 40];  // +8 bf16 row pad
    __shared__ bf16 Bs[64 * 40];
    int t = threadIdx.x;
    int w = t >> 6, lane = t & 63;
    int lrow = lane & 15, lk = lane >> 4;
    f32x4 acc[4] = {};
    int r = t >> 2, cc = (t & 3) * 8;
    for (int kc = 0; kc < 256; kc += 32) {
        u32x4 va = *(const u32x4*)(A + (size_t)(m0 + r) * 256 + kc + cc);
        u32x4 vbv = *(const u32x4*)(Bt + ((size_t)b * Nrows + n0 + r) * 256 + kc + cc);
        *(u32x4*)(As + r * 40 + cc) = va;
        *(u32x4*)(Bs + r * 40 + cc) = vbv;
        __syncthreads();
        bf16x8 af = *(const bf16x8*)(As + (w * 16 + lrow) * 40 + lk * 8);
#pragma unroll
        for (int ct = 0; ct < 4; ct++) {
            bf16x8 bfr = *(const bf16x8*)(Bs + (ct * 16 + lrow) * 40 + lk * 8);
            acc[ct] = MFMA16(af, bfr, acc[ct], 0, 0, 0);
        }
        __syncthreads();
    }
    // C/D layout: col = lane&15, row = (lane>>4)*4 + reg  [verified m89/m91]
    int o0 = m0 + w * 16 + lk * 4;
    f32x4 b4 = *(const f32x4*)(bias + o0);
    int head = o0 >> 5;
#pragma unroll
    for (int ct = 0; ct < 4; ct++) {
        int n = n0 + ct * 16 + lrow;
        if (mode == 0) {
            bf16* Dst = (head, Qb); // placeholder to appease nothing
            Dst = (oscale == 1.0f && Nrows == 3072) ? Kb : Qb;
            int dd = o0 & 31;
            bf16x4 pv;
#pragma unroll
            for (int j = 0; j < 4; j++) pv[j] = (bf16)((acc[ct][j] + b4[j]) * oscale);
            *(bf16x4*)(Dst + ((size_t)(b * 8 + head) * Nrows + n) * 32 + dd) = pv;
        } else {
#pragma unroll
            for (int j = 0; j < 4; j++) {
                int dd = (o0 & 31) + j;
                int kk = ((dd & 7) << 1) | ((dd >> 3) & 1);
                int u = n & 63, g = u >> 2;
                int col = n0 + ((g ^ kk) << 2) + (u & 3);
                Vtb[((size_t)(b * 8 + head) * 32 + dd) * 3072 + col] = (f16)(acc[ct][j] + b4[j]);
            }
        }
    }
}

// ---------------------------------------------------------------------------
// K2: attention, S^T formulation — zero P LDS round-trip.
//   S^T = K·Q^T  (A=K frag, B=Q frag, 16x16x32 bf16): C/D row=kn_local, col=q.
//   exp2(S^T) in registers IS a valid f16 B-operand (B[k=quad*4+j][n=q]) for
//   v_mfma_f32_16x16x16f16, so PV computes out^T[d][q] += V^T · P^T directly
//   from registers. Row-sums L via ones-A MFMA (colsum, accumulated over kn).
// 32 q-rows/wave (2 Q B-frags) so K/V LDS fragment reads amortize over 2x work.
// K/V async-staged to dbuf LDS; V's LDS image uses a d-keyed XOR granule
// swizzle (pre-baked in k_qkv) making b64 A-frag reads bank-floor.
// Split-kn=2; partials Opart[sp*16+bh][32 d][4096 q] f32, Lsum f32.
__global__ __launch_bounds__(256, 4) void k_attn(const bf16* __restrict__ Q, const bf16* __restrict__ K,
                                                 const f16* __restrict__ Vt,
                                                 float* __restrict__ Opart, float* __restrict__ Lsum) {
    int bh = blockIdx.y;
    int q0 = blockIdx.x * 128;
    int sp = blockIdx.z;             // kn split half
    int kn0 = sp * 1536;
    int t = threadIdx.x, w = t >> 6, lane = t & 63;
    int lrow = lane & 15, lk = lane >> 4;
    __shared__ bf16 Ks[2][64 * 32];   // [kn][d]
    __shared__ f16 Vs[2][32 * 64];    // [d][kn-image], xor granule swizzle
    const bf16* kbase = K + (size_t)bh * 3072 * 32;
    const f16* vbase = Vt + (size_t)bh * 32 * 3072;
    const bf16* kg = kbase + (size_t)(kn0 + w * 16 + (lane >> 2)) * 32 + (lane & 3) * 8;
    const f16* vg = vbase + (size_t)(w * 8 + (lane >> 3)) * 3072 + kn0 + (lane & 7) * 8;
    // Q as B-operand: B[k=d=lk*8+j][n=q=lrow]
    const bf16* qrow = Q + ((size_t)bh * 4096 + q0 + w * 32 + lrow) * 32 + lk * 8;
    bf16x8 aq0 = *(const bf16x8*)(qrow);
    bf16x8 aq1 = *(const bf16x8*)(qrow + 16 * 32);
    f16x4 ones;
    ones[0] = (f16)1.f; ones[1] = (f16)1.f; ones[2] = (f16)1.f; ones[3] = (f16)1.f;
    f32x4 accO[2][2] = {};   // [q-group][d-half]
    f32x4 accL[2] = {};
    f32x4 zero = {};
    int kk2 = ((lrow & 7) << 1) | (lrow >> 3);   // V swizzle key (d&15 = lrow)
    async16(&Ks[0][w * 512], kg);
    async16(&Vs[0][w * 512], vg);
    __syncthreads();
    for (int c = 0; c < 24; ++c) {
        int buf = c & 1;
        if (c < 23) {
            int kc1 = (c + 1) * 64;
            async16(&Ks[buf ^ 1][w * 512], kg + (size_t)kc1 * 32);
            async16(&Vs[buf ^ 1][w * 512], vg + kc1);
        }
        const bf16* ksb = &Ks[buf][0];
        const f16* vsb = &Vs[buf][0];
        // S^T: A = K[16jt+lrow][d], B = Q — same read patterns as before
        f32x4 s0[4], s1[4];
#pragma unroll
        for (int jt = 0; jt < 4; ++jt) {
            bf16x8 kf = *(const bf16x8*)(ksb + (16 * jt + lrow) * 32 + lk * 8);
            s0[jt] = MFMA16(kf, aq0, zero, 0, 0, 0);
            s1[jt] = MFMA16(kf, aq1, zero, 0, 0, 0);
        }
#pragma unroll
        for (int jt = 0; jt < 4; ++jt) {
            f16x4 p0, p1;
#pragma unroll
            for (int i = 0; i < 4; ++i) {
                p0[i] = (f16)__builtin_amdgcn_exp2f(s0[jt][i]);
                p1[i] = (f16)__builtin_amdgcn_exp2f(s1[jt][i]);
            }
            // V^T A-frag: A[m=d][k=kn_local=lk*4+j] via swizzled image
            int gcol = (((jt << 2) | lk) ^ kk2) << 2;
            f16x4 vf0 = *(const f16x4*)(vsb + lrow * 64 + gcol);
            f16x4 vf1 = *(const f16x4*)(vsb + (16 + lrow) * 64 + gcol);
            accO[0][0] = MFMA16F(vf0, p0, accO[0][0], 0, 0, 0);
            accO[0][1] = MFMA16F(vf1, p0, accO[0][1], 0, 0, 0);
            accO[1][0] = MFMA16F(vf0, p1, accO[1][0], 0, 0, 0);
            accO[1][1] = MFMA16F(vf1, p1, accO[1][1], 0, 0, 0);
            accL[0] = MFMA16F(ones, p0, accL[0], 0, 0, 0);
            accL[1] = MFMA16F(ones, p1, accL[1], 0, 0, 0);
        }
        __syncthreads();
    }
    // out^T C/D: row = d_local = lk*4+i, col = q = lrow. Coalesced dword stores.
    int sb = sp * 16 + bh;
    float* Ob = Opart + (size_t)sb * 32 * 4096;
#pragma unroll
    for (int qg = 0; qg < 2; ++qg) {
        int q = q0 + w * 32 + qg * 16 + lrow;
#pragma unroll
        for (int dh = 0; dh < 2; ++dh)
#pragma unroll
            for (int i = 0; i < 4; ++i)
                Ob[(size_t)(dh * 16 + lk * 4 + i) * 4096 + q] = accO[qg][dh][i];
        if (lane < 16) Lsum[(size_t)sb * 4096 + q] = accL[qg][0];
    }
}

// ---------------------------------------------------------------------------
// K3: o-projection with fused split-kn combine in the B-staging.
// Opart is [sb][32 d][4096 q]; thread (r=q-row, cc=d-group) reads 8+8 scalars
// at stride 4096 (L2-resident; 16 q x 4B = 64B segments per instr group).
__global__ __launch_bounds__(256) void k_oproj(const bf16* __restrict__ A, const float* __restrict__ Opart,
                                               const float* __restrict__ Ls, const float* __restrict__ bias,
                                               float* __restrict__ opre) {
    int i = blockIdx.x;
    int n0 = (i & 63) * 64, m0 = ((i >> 6) & 3) * 64, b = i >> 8;
    __shared__ bf16 As[64 * 40];
    __shared__ bf16 Bs[64 * 40];
    int t = threadIdx.x;
    int w = t >> 6, lane = t & 63;
    int lrow = lane & 15, lk = lane >> 4;
    f32x4 acc[4] = {};
    int r = t >> 2, cc = (t & 3) * 8;
    int q = n0 + r;
    for (int kc = 0; kc < 256; kc += 32) {
        int h = kc >> 5, bh = b * 8 + h;
        u32x4 va = *(const u32x4*)(A + (size_t)(m0 + r) * 256 + kc + cc);
        const float* o1 = Opart + ((size_t)bh * 32 + cc) * 4096 + q;
        const float* o2 = o1 + (size_t)16 * 32 * 4096;
        float l = Ls[(size_t)bh * 4096 + q] + Ls[(size_t)(16 + bh) * 4096 + q];
        float rl = 1.0f / l;
        bf16x8 bb;
#pragma unroll
        for (int u = 0; u < 8; ++u)
            bb[u] = (bf16)((o1[(size_t)u * 4096] + o2[(size_t)u * 4096]) * rl);
        *(u32x4*)(As + r * 40 + cc) = va;
        *(bf16x8*)(Bs + r * 40 + cc) = bb;
        __syncthreads();
        bf16x8 af = *(const bf16x8*)(As + (w * 16 + lrow) * 40 + lk * 8);
#pragma unroll
        for (int ct = 0; ct < 4; ct++) {
            bf16x8 bfr = *(const bf16x8*)(Bs + (ct * 16 + lrow) * 40 + lk * 8);
            acc[ct] = MFMA16(af, bfr, acc[ct], 0, 0, 0);
        }
        __syncthreads();
    }
    int o0 = m0 + w * 16 + lk * 4;
    f32x4 b4 = *(const f32x4*)(bias + o0);
#pragma unroll
    for (int ct = 0; ct < 4; ct++) {
        int n = n0 + ct * 16 + lrow;
        f32x4 v;
#pragma unroll
        for (int j = 0; j < 4; j++) v[j] = acc[ct][j] + b4[j];
        *(f32x4*)(opre + ((size_t)b * 4096 + n) * 256 + o0) = v;
    }
}

// ---------------------------------------------------------------------------
// K4: residual + LayerNorm(C) + transpose back to [b][c][n]. Tile 32n x 256c.
__global__ __launch_bounds__(256) void k_ln(const float* __restrict__ opre, const float* __restrict__ s3,
                                            const float* __restrict__ lnw, const float* __restrict__ lnb,
                                            float* __restrict__ out) {
    int b = blockIdx.y;
    int n0 = blockIdx.x * 32;
    __shared__ float T[32][257];
    __shared__ float mu_s[32], rs_s[32];
    int t = threadIdx.x;
#pragma unroll
    for (int i = 0; i < 8; i++) {
        int flat = i * 256 + t;
        int n = flat >> 6;
        int c = (flat & 63) * 4;
        f32x4 v = *(const f32x4*)(opre + ((size_t)b * 4096 + n0 + n) * 256 + c);
        T[n][c + 0] = v[0]; T[n][c + 1] = v[1]; T[n][c + 2] = v[2]; T[n][c + 3] = v[3];
    }
    __syncthreads();
#pragma unroll
    for (int i = 0; i < 8; i++) {
        int flat = i * 256 + t;
        int c = flat >> 3;
        int n = (flat & 7) * 4;
        f32x4 v = *(const f32x4*)(s3 + ((size_t)b * 256 + c) * 4096 + n0 + n);
        T[n + 0][c] += v[0]; T[n + 1][c] += v[1]; T[n + 2][c] += v[2]; T[n + 3][c] += v[3];
    }
    __syncthreads();
    int w = t >> 6, lane = t & 63;
    for (int j = 0; j < 8; j++) {
        int row = w * 8 + j;
        float x0 = T[row][lane], x1 = T[row][lane + 64];
        float x2 = T[row][lane + 128], x3 = T[row][lane + 192];
        float s = x0 + x1 + x2 + x3;
        float s2 = x0 * x0 + x1 * x1 + x2 * x2 + x3 * x3;
#pragma unroll
        for (int off = 1; off < 64; off <<= 1) {
            s += __shfl_xor(s, off, 64);
            s2 += __shfl_xor(s2, off, 64);
        }
        if (lane == 0) {
            float mu = s * (1.0f / 256.0f);
            float var = s2 * (1.0f / 256.0f) - mu * mu;
            mu_s[row] = mu;
            rs_s[row] = rsqrtf(var + 1e-5f);
        }
    }
    __syncthreads();
    int c = t;
    float wv = lnw[c], bv = lnb[c];
#pragma unroll
    for (int i = 0; i < 8; i++) {
        int n = i * 4;
        f32x4 o;
#pragma unroll
        for (int k = 0; k < 4; k++)
            o[k] = (T[n + k][c] - mu_s[n + k]) * rs_s[n + k] * wv + bv;
        *(f32x4*)(out + ((size_t)b * 256 + c) * 4096 + n0 + n) = o;
    }
}

// ---------------------------------------------------------------------------
extern "C" void kernel_launch(void* const* d_in, const int* in_sizes, int n_in,
                              void* d_out, int out_size, void* d_ws, size_t ws_size,
                              hipStream_t stream) {
    const float* s3  = (const float*)d_in[0];
    const float* s4  = (const float*)d_in[1];
    const float* s5  = (const float*)d_in[2];
    const float* qw  = (const float*)d_in[3];
    const float* qb  = (const float*)d_in[4];
    const float* kw  = (const float*)d_in[5];
    const float* kb  = (const float*)d_in[6];
    const float* vw  = (const float*)d_in[7];
    const float* vb  = (const float*)d_in[8];
    const float* ow  = (const float*)d_in[9];
    const float* ob  = (const float*)d_in[10];
    const float* lnw = (const float*)d_in[11];
    const float* lnb = (const float*)d_in[12];
    float* out = (float*)d_out;
    char* ws = (char*)d_ws;

    // workspace layout (34 MB peak, with dead-buffer overlays):
    bf16* Wb    = (bf16*)(ws);                          // 512 KB @ 0
    bf16* s3t   = (bf16*)(ws + (512ull << 10));         // 4 MB  @ 0.5 MB
    bf16* s45t  = (bf16*)(ws + (4608ull << 10));        // 3 MB  @ 4.5 MB
    bf16* Qb    = (bf16*)(ws + (7680ull << 10));        // 4 MB  @ 7.5 MB
    bf16* Kb    = Qb + (2ull * 8 * 4096 * 32);          // 3 MB  @ 11.5 MB
    f16*  Vtb   = (f16*)(Kb + (2ull * 8 * 3072 * 32));  // 3 MB  @ 14.5 MB
    float* Opart = (float*)(ws + (17920ull << 10));     // 16 MB @ 17.5 MB
    float* Lsum  = (float*)(ws + (34304ull << 10));     // 512 KB @ 33.5 MB
    float* opre  = (float*)(ws + (512ull << 10));       // 8 MB @ 0.5 (dead buffers post-attn)

    // fold softmax scale * log2(e) into Q so k_attn uses exp2 directly
    const float qscale = 0.17677669529663688f * 1.4426950408889634f;

    k_prep<<<1152, 256, 0, stream>>>(qw, kw, vw, ow, Wb, s3, s4, s5, s3t, s45t);
    k_qkv<<<1280, 256, 0, stream>>>(Wb, s3t, s45t, qb, kb, vb, Qb, Kb, Vtb, qscale);
    k_attn<<<dim3(32, 16, 2), 256, 0, stream>>>(Qb, Kb, Vtb, Opart, Lsum);
    k_oproj<<<512, 256, 0, stream>>>(Wb + 196608, Opart, Lsum, ob, opre);
    k_ln<<<dim3(128, 2), 256, 0, stream>>>(opre, s3, lnw, lnb, out);
}

// Round 7
// 154.724 us; speedup vs baseline: 1.6919x; 1.0461x over previous
//
#include <hip/hip_runtime.h>

typedef __bf16 bf16;
typedef __bf16 bf16x4 __attribute__((ext_vector_type(4)));
typedef __bf16 bf16x8 __attribute__((ext_vector_type(8)));
typedef _Float16 f16;
typedef _Float16 f16x2 __attribute__((ext_vector_type(2)));
typedef _Float16 f16x8 __attribute__((ext_vector_type(8)));
typedef float f32x4 __attribute__((ext_vector_type(4)));
typedef unsigned int u32x4 __attribute__((ext_vector_type(4)));

#define MFMA16 __builtin_amdgcn_mfma_f32_16x16x32_bf16
#define MFMA16H __builtin_amdgcn_mfma_f32_16x16x32_f16

// async 16B/lane global->LDS copy; HW scatters lane i to lds + i*16 (wave-uniform base)
__device__ __forceinline__ void async16(void* lds, const void* g) {
    __builtin_amdgcn_global_load_lds((const __attribute__((address_space(1))) unsigned int*)g,
                                     (__attribute__((address_space(3))) unsigned int*)lds, 16, 0, 0);
}

// packed f32x2 -> f16x2 (cvt_pkrtz returns __fp16-based vector; bit-cast to _Float16-based)
__device__ __forceinline__ f16x2 pkrtz(float a, float b) {
    return __builtin_bit_cast(f16x2, __builtin_amdgcn_cvt_pkrtz(a, b));
}

__device__ __forceinline__ float fdot2h(f16x2 a, f16x2 b, float c) {
#if __has_builtin(__builtin_amdgcn_fdot2)
    return __builtin_amdgcn_fdot2(a, b, c, false);
#else
    return c + (float)a[0] * (float)b[0] + (float)a[1] * (float)b[1];
#endif
}

// ---------------------------------------------------------------------------
// K0 "prep": weight cvt (blocks 0..255) + three activation transposes
// (s3: 256..767, s4: 768..1023, s5: 1024..1151).
__global__ __launch_bounds__(256) void k_prep(const float* __restrict__ qw, const float* __restrict__ kw,
                                              const float* __restrict__ vw, const float* __restrict__ ow,
                                              bf16* __restrict__ Wb,
                                              const float* __restrict__ s3, const float* __restrict__ s4,
                                              const float* __restrict__ s5,
                                              bf16* __restrict__ s3t, bf16* __restrict__ s45t) {
    __shared__ float T[64][65];
    int bx = blockIdx.x, t = threadIdx.x;
    if (bx < 256) {
        int tt = bx * 256 + t;
        const float* srcs[4] = {qw, kw, vw, ow};
        int which = tt >> 14;
        int idx = (tt & 16383) * 4;
        f32x4 v = *(const f32x4*)(srcs[which] + idx);
        bf16x4 o;
        o[0] = (bf16)v[0]; o[1] = (bf16)v[1]; o[2] = (bf16)v[2]; o[3] = (bf16)v[3];
        *(bf16x4*)(Wb + (size_t)which * 65536 + idx) = o;
        return;
    }
    const float* src; bf16* dst; int N, dstRows, rowOff, x, y, z;
    if (bx < 768)       { int i = bx - 256;  src = s3; dst = s3t;  N = 4096; dstRows = 4096; rowOff = 0;    x = i & 63; y = (i >> 6) & 3; z = i >> 8; }
    else if (bx < 1024) { int i = bx - 768;  src = s4; dst = s45t; N = 2048; dstRows = 3072; rowOff = 0;    x = i & 31; y = (i >> 5) & 3; z = i >> 7; }
    else                { int i = bx - 1024; src = s5; dst = s45t; N = 1024; dstRows = 3072; rowOff = 2048; x = i & 15; y = (i >> 4) & 3; z = i >> 6; }
    int c0 = y * 64, n0 = x * 64, b = z;
    const float* s = src + ((size_t)b * 256 + c0) * N + n0;
#pragma unroll
    for (int i = 0; i < 4; i++) {
        int flat = i * 256 + t;
        int row = flat >> 4;
        int col = (flat & 15) * 4;
        f32x4 v = *(const f32x4*)(s + (size_t)row * N + col);
        T[row][col + 0] = v[0]; T[row][col + 1] = v[1];
        T[row][col + 2] = v[2]; T[row][col + 3] = v[3];
    }
    __syncthreads();
#pragma unroll
    for (int i = 0; i < 4; i++) {
        int flat = i * 256 + t;
        int nrow = flat >> 4;
        int c4 = (flat & 15) * 4;
        bf16x4 o;
        o[0] = (bf16)T[c4 + 0][nrow]; o[1] = (bf16)T[c4 + 1][nrow];
        o[2] = (bf16)T[c4 + 2][nrow]; o[3] = (bf16)T[c4 + 3][nrow];
        *(bf16x4*)(dst + ((size_t)(b * dstRows + rowOff + n0 + nrow)) * 256 + c0 + c4) = o;
    }
}

// ---------------------------------------------------------------------------
// K1 "qkv": Q blocks 0..511 (mode 0), K 512..895 (mode 1), V 896..1279 (mode 2).
// mode 0: Q bf16 [bh][n][32], pre-scaled by 32^-.5*log2e.
// mode 1: K bf16 [bh][n'][32] with n' row-permuted within 32-blocks:
//         u=n&31 -> np = ((u>>2)&1)<<4 | (u>>3)<<2 | (u&3), so that k_attn's
//         two 16-row S^T tiles concatenate into a K=32 MFMA B-operand.
// mode 2: V f16 [bh][32 d][3072 kn] with kn permuted per 64-chunk by a d-keyed
//         XOR on 8-elem granules: col = (n&~63) + ((g^(d&7))<<3) + (n&7),
//         g=(n&63)>>3 — the exact LDS image k_attn's b128 V A-frag reads want.
__global__ __launch_bounds__(256) void k_qkv(const bf16* __restrict__ Wb,
                                             const bf16* __restrict__ s3t, const bf16* __restrict__ s45t,
                                             const float* __restrict__ qb, const float* __restrict__ kb,
                                             const float* __restrict__ vb,
                                             bf16* __restrict__ Qb, bf16* __restrict__ Kb,
                                             f16* __restrict__ Vtb, float qscale) {
    int i = blockIdx.x;
    int mode, n0, m0, b, Nrows;
    const bf16 *A, *Bt; const float* bias; float oscale = 1.0f;
    if (i < 512) {
        mode = 0; A = Wb; Bt = s3t; bias = qb; Nrows = 4096; oscale = qscale;
        n0 = (i & 63) * 64; m0 = ((i >> 6) & 3) * 64; b = i >> 8;
    } else if (i < 896) {
        unsigned j = i - 512;
        mode = 1; A = Wb + 65536; Bt = s45t; bias = kb; Nrows = 3072;
        n0 = (j % 48u) * 64; unsigned rr = j / 48u; m0 = (rr & 3) * 64; b = rr >> 2;
    } else {
        unsigned j = i - 896;
        mode = 2; A = Wb + 131072; Bt = s45t; bias = vb; Nrows = 3072;
        n0 = (j % 48u) * 64; unsigned rr = j / 48u; m0 = (rr & 3) * 64; b = rr >> 2;
    }
    __shared__ bf16 As[64 * 40];
    __shared__ bf16 Bs[64 * 40];
    int t = threadIdx.x;
    int w = t >> 6, lane = t & 63;
    int lrow = lane & 15, lk = lane >> 4;
    f32x4 acc[4] = {};
    int r = t >> 2, cc = (t & 3) * 8;
    for (int kc = 0; kc < 256; kc += 32) {
        u32x4 va = *(const u32x4*)(A + (size_t)(m0 + r) * 256 + kc + cc);
        u32x4 vbv = *(const u32x4*)(Bt + ((size_t)b * Nrows + n0 + r) * 256 + kc + cc);
        *(u32x4*)(As + r * 40 + cc) = va;
        *(u32x4*)(Bs + r * 40 + cc) = vbv;
        __syncthreads();
        bf16x8 af = *(const bf16x8*)(As + (w * 16 + lrow) * 40 + lk * 8);
#pragma unroll
        for (int ct = 0; ct < 4; ct++) {
            bf16x8 bfr = *(const bf16x8*)(Bs + (ct * 16 + lrow) * 40 + lk * 8);
            acc[ct] = MFMA16(af, bfr, acc[ct], 0, 0, 0);
        }
        __syncthreads();
    }
    // C/D layout: col = lane&15, row = (lane>>4)*4 + reg  [verified m89/m91]
    int o0 = m0 + w * 16 + lk * 4;
    f32x4 b4 = *(const f32x4*)(bias + o0);
    int head = o0 >> 5;
#pragma unroll
    for (int ct = 0; ct < 4; ct++) {
        int n = n0 + ct * 16 + lrow;
        if (mode == 0) {
            int dd = o0 & 31;
            bf16x4 pv;
#pragma unroll
            for (int j = 0; j < 4; j++) pv[j] = (bf16)((acc[ct][j] + b4[j]) * oscale);
            *(bf16x4*)(Qb + ((size_t)(b * 8 + head) * 4096 + n) * 32 + dd) = pv;
        } else if (mode == 1) {
            int dd = o0 & 31;
            int u = n & 31;
            int np = (n & ~31) | (((u >> 2) & 1) << 4) | ((u >> 3) << 2) | (u & 3);
            bf16x4 pv;
#pragma unroll
            for (int j = 0; j < 4; j++) pv[j] = (bf16)(acc[ct][j] + b4[j]);
            *(bf16x4*)(Kb + ((size_t)(b * 8 + head) * 3072 + np) * 32 + dd) = pv;
        } else {
            int g = (n & 63) >> 3;
#pragma unroll
            for (int j = 0; j < 4; j++) {
                int dd = (o0 & 31) + j;
                int col = (n & ~63) + ((g ^ (dd & 7)) << 3) + (n & 7);
                Vtb[((size_t)(b * 8 + head) * 32 + dd) * 3072 + col] = (f16)(acc[ct][j] + b4[j]);
            }
        }
    }
}

// ---------------------------------------------------------------------------
// K2: attention. S^T = K·Q^T (bf16 16x16x32); K's global row-perm makes two
// 16-row S^T tiles' exp2'd C/D registers a bit-exact K=32 f16 B-operand, so
// PV runs at full rate via mfma_f32_16x16x32_f16 with V^T as A (from the
// XOR-imaged LDS tile): out^T[d][q] += V^T·P^T, all register-resident P.
// L row-sums: fdot2 per-lane partials + 2 shuffles (no MFMA).
// Block = 4 waves x 64q = 256 q; kn chunk 64, dbuf async LDS; split-kn=4.
// Epilogue: per-wave LDS transpose -> Opart f16 [sb][q][32 d], coalesced 16B.
__global__ __launch_bounds__(256, 4) void k_attn(const bf16* __restrict__ Q, const bf16* __restrict__ K,
                                                 const f16* __restrict__ Vt,
                                                 f16* __restrict__ Opart, float* __restrict__ Lsum) {
    int bh = blockIdx.y;
    int q0 = blockIdx.x * 256;
    int sp = blockIdx.z;
    int kn0 = sp * 768;
    int t = threadIdx.x, w = t >> 6, lane = t & 63;
    int lrow = lane & 15, lk = lane >> 4;
    __shared__ bf16 Ks[2][64 * 32];   // [kn-rows (perm baked in global)][d]
    __shared__ f16 Vs[2][32 * 64];    // [d][kn-image (XOR baked in global)]
    __shared__ f16 Tq[4][32 * 66];    // per-wave epilogue transpose
    const bf16* kbase = K + (size_t)bh * 3072 * 32;
    const f16* vbase = Vt + (size_t)bh * 32 * 3072;
    const bf16* kg = kbase + (size_t)(kn0 + w * 16 + (lane >> 2)) * 32 + (lane & 3) * 8;
    const f16* vg = vbase + (size_t)(w * 8 + (lane >> 3)) * 3072 + kn0 + (lane & 7) * 8;
    // Q as B-operand: B[k=d=lk*8+j][n=q=lrow], one frag per 16-q group
    bf16x8 aq[4];
#pragma unroll
    for (int qg = 0; qg < 4; ++qg)
        aq[qg] = *(const bf16x8*)(Q + ((size_t)bh * 4096 + q0 + w * 64 + qg * 16 + lrow) * 32 + lk * 8);
    f32x4 accO[4][2] = {};   // [q-group][d-half], out^T: row=d_local, col=q
    float lsum[4] = {0.f, 0.f, 0.f, 0.f};
    f32x4 zero = {};
    f16x2 one2; one2[0] = (f16)1.f; one2[1] = (f16)1.f;
    int vkey = lrow & 7;     // V image XOR key = d&7 (same for both d-halves)
    async16(&Ks[0][w * 512], kg);
    async16(&Vs[0][w * 512], vg);
    __syncthreads();
    for (int c = 0; c < 12; ++c) {
        int buf = c & 1;
        if (c < 11) {
            async16(&Ks[buf ^ 1][w * 512], kg + (size_t)(c + 1) * 64 * 32);
            async16(&Vs[buf ^ 1][w * 512], vg + (c + 1) * 64);
        }
        const bf16* ksb = &Ks[buf][0];
        const f16* vsb = &Vs[buf][0];
#pragma unroll
        for (int p = 0; p < 2; ++p) {   // two 32-kn chunks
            f32x4 s[2][4];
#pragma unroll
            for (int t2 = 0; t2 < 2; ++t2) {
                bf16x8 kf = *(const bf16x8*)(ksb + (p * 32 + t2 * 16 + lrow) * 32 + lk * 8);
#pragma unroll
                for (int qg = 0; qg < 4; ++qg) s[t2][qg] = MFMA16(kf, aq[qg], zero, 0, 0, 0);
            }
            // exp2 + pack: p8[qg] element j' = (t2,i) -> kn = 32p + 8*lk + j'
            f16x8 p8[4];
#pragma unroll
            for (int qg = 0; qg < 4; ++qg) {
                f16x2 h0 = pkrtz(__builtin_amdgcn_exp2f(s[0][qg][0]), __builtin_amdgcn_exp2f(s[0][qg][1]));
                f16x2 h1 = pkrtz(__builtin_amdgcn_exp2f(s[0][qg][2]), __builtin_amdgcn_exp2f(s[0][qg][3]));
                f16x2 h2 = pkrtz(__builtin_amdgcn_exp2f(s[1][qg][0]), __builtin_amdgcn_exp2f(s[1][qg][1]));
                f16x2 h3 = pkrtz(__builtin_amdgcn_exp2f(s[1][qg][2]), __builtin_amdgcn_exp2f(s[1][qg][3]));
                f16x8 pk;
                pk[0] = h0[0]; pk[1] = h0[1]; pk[2] = h1[0]; pk[3] = h1[1];
                pk[4] = h2[0]; pk[5] = h2[1]; pk[6] = h3[0]; pk[7] = h3[1];
                p8[qg] = pk;
                lsum[qg] = fdot2h(h0, one2, lsum[qg]);
                lsum[qg] = fdot2h(h1, one2, lsum[qg]);
                lsum[qg] = fdot2h(h2, one2, lsum[qg]);
                lsum[qg] = fdot2h(h3, one2, lsum[qg]);
            }
#pragma unroll
            for (int dh = 0; dh < 2; ++dh) {
                f16x8 vf = *(const f16x8*)(vsb + (dh * 16 + lrow) * 64 + ((((p << 2) | lk) ^ vkey) << 3));
#pragma unroll
                for (int qg = 0; qg < 4; ++qg)
                    accO[qg][dh] = MFMA16H(vf, p8[qg], accO[qg][dh], 0, 0, 0);
            }
        }
        __syncthreads();
    }
    // L: reduce per-lane partials over lk (lanes lrow, lrow+16, +32, +48)
    int sb = sp * 16 + bh;
#pragma unroll
    for (int qg = 0; qg < 4; ++qg) {
        lsum[qg] += __shfl_xor(lsum[qg], 16, 64);
        lsum[qg] += __shfl_xor(lsum[qg], 32, 64);
    }
    if (lane < 16) {
#pragma unroll
        for (int qg = 0; qg < 4; ++qg)
            Lsum[(size_t)sb * 4096 + q0 + w * 64 + qg * 16 + lane] = lsum[qg];
    }
    // O epilogue: same-wave LDS transpose [d][q] -> coalesced [q][d] f16 stores
    f16* tw = &Tq[w][0];
#pragma unroll
    for (int qg = 0; qg < 4; ++qg)
#pragma unroll
        for (int dh = 0; dh < 2; ++dh)
#pragma unroll
            for (int i = 0; i < 4; ++i)
                tw[(dh * 16 + lk * 4 + i) * 66 + qg * 16 + lrow] = (f16)accO[qg][dh][i];
    int q4 = (lane & 15) * 4, dgrp = (lane >> 4) * 8;
#pragma unroll
    for (int qq = 0; qq < 4; ++qq) {
        f16x8 ov;
#pragma unroll
        for (int dj = 0; dj < 8; ++dj) ov[dj] = tw[(dgrp + dj) * 66 + q4 + qq];
        *(f16x8*)(Opart + ((size_t)sb * 4096 + q0 + w * 64 + q4 + qq) * 32 + dgrp) = ov;
    }
}

// ---------------------------------------------------------------------------
// K3: o-projection with fused 4-way split-kn combine in the B-staging.
// Opart [sb][q][32 d] f16 -> coalesced f16x8 loads, sum, *1/L, cvt bf16,
// b128 Bs write (the proven staging pattern). Each kc tile = one head.
__global__ __launch_bounds__(256) void k_oproj(const bf16* __restrict__ A, const f16* __restrict__ Opart,
                                               const float* __restrict__ Ls, const float* __restrict__ bias,
                                               float* __restrict__ opre) {
    int i = blockIdx.x;
    int n0 = (i & 63) * 64, m0 = ((i >> 6) & 3) * 64, b = i >> 8;
    __shared__ bf16 As[64 * 40];
    __shared__ bf16 Bs[64 * 40];
    int t = threadIdx.x;
    int w = t >> 6, lane = t & 63;
    int lrow = lane & 15, lk = lane >> 4;
    f32x4 acc[4] = {};
    int r = t >> 2, cc = (t & 3) * 8;
    int q = n0 + r;
    const size_t SPS = (size_t)16 * 4096 * 32;   // Opart sp stride (elems)
    for (int kc = 0; kc < 256; kc += 32) {
        int bh = b * 8 + (kc >> 5);
        u32x4 va = *(const u32x4*)(A + (size_t)(m0 + r) * 256 + kc + cc);
        float l = Ls[(size_t)bh * 4096 + q] + Ls[(size_t)(16 + bh) * 4096 + q] +
                  Ls[(size_t)(32 + bh) * 4096 + q] + Ls[(size_t)(48 + bh) * 4096 + q];
        float rl = 1.0f / l;
        const f16* ob = Opart + ((size_t)bh * 4096 + q) * 32 + cc;
        f16x8 a0 = *(const f16x8*)(ob);
        f16x8 a1 = *(const f16x8*)(ob + SPS);
        f16x8 a2 = *(const f16x8*)(ob + 2 * SPS);
        f16x8 a3 = *(const f16x8*)(ob + 3 * SPS);
        bf16x8 bb;
#pragma unroll
        for (int j = 0; j < 8; ++j)
            bb[j] = (bf16)((((float)a0[j] + (float)a1[j]) + ((float)a2[j] + (float)a3[j])) * rl);
        *(u32x4*)(As + r * 40 + cc) = va;
        *(bf16x8*)(Bs + r * 40 + cc) = bb;
        __syncthreads();
        bf16x8 af = *(const bf16x8*)(As + (w * 16 + lrow) * 40 + lk * 8);
#pragma unroll
        for (int ct = 0; ct < 4; ct++) {
            bf16x8 bfr = *(const bf16x8*)(Bs + (ct * 16 + lrow) * 40 + lk * 8);
            acc[ct] = MFMA16(af, bfr, acc[ct], 0, 0, 0);
        }
        __syncthreads();
    }
    int o0 = m0 + w * 16 + lk * 4;
    f32x4 b4 = *(const f32x4*)(bias + o0);
#pragma unroll
    for (int ct = 0; ct < 4; ct++) {
        int n = n0 + ct * 16 + lrow;
        f32x4 v;
#pragma unroll
        for (int j = 0; j < 4; j++) v[j] = acc[ct][j] + b4[j];
        *(f32x4*)(opre + ((size_t)b * 4096 + n) * 256 + o0) = v;
    }
}

// ---------------------------------------------------------------------------
// K4: residual + LayerNorm(C) + transpose back to [b][c][n]. Tile 32n x 256c.
__global__ __launch_bounds__(256) void k_ln(const float* __restrict__ opre, const float* __restrict__ s3,
                                            const float* __restrict__ lnw, const float* __restrict__ lnb,
                                            float* __restrict__ out) {
    int b = blockIdx.y;
    int n0 = blockIdx.x * 32;
    __shared__ float T[32][257];
    __shared__ float mu_s[32], rs_s[32];
    int t = threadIdx.x;
#pragma unroll
    for (int i = 0; i < 8; i++) {
        int flat = i * 256 + t;
        int n = flat >> 6;
        int c = (flat & 63) * 4;
        f32x4 v = *(const f32x4*)(opre + ((size_t)b * 4096 + n0 + n) * 256 + c);
        T[n][c + 0] = v[0]; T[n][c + 1] = v[1]; T[n][c + 2] = v[2]; T[n][c + 3] = v[3];
    }
    __syncthreads();
#pragma unroll
    for (int i = 0; i < 8; i++) {
        int flat = i * 256 + t;
        int c = flat >> 3;
        int n = (flat & 7) * 4;
        f32x4 v = *(const f32x4*)(s3 + ((size_t)b * 256 + c) * 4096 + n0 + n);
        T[n + 0][c] += v[0]; T[n + 1][c] += v[1]; T[n + 2][c] += v[2]; T[n + 3][c] += v[3];
    }
    __syncthreads();
    int w = t >> 6, lane = t & 63;
    for (int j = 0; j < 8; j++) {
        int row = w * 8 + j;
        float x0 = T[row][lane], x1 = T[row][lane + 64];
        float x2 = T[row][lane + 128], x3 = T[row][lane + 192];
        float s = x0 + x1 + x2 + x3;
        float s2 = x0 * x0 + x1 * x1 + x2 * x2 + x3 * x3;
#pragma unroll
        for (int off = 1; off < 64; off <<= 1) {
            s += __shfl_xor(s, off, 64);
            s2 += __shfl_xor(s2, off, 64);
        }
        if (lane == 0) {
            float mu = s * (1.0f / 256.0f);
            float var = s2 * (1.0f / 256.0f) - mu * mu;
            mu_s[row] = mu;
            rs_s[row] = rsqrtf(var + 1e-5f);
        }
    }
    __syncthreads();
    int c = t;
    float wv = lnw[c], bv = lnb[c];
#pragma unroll
    for (int i = 0; i < 8; i++) {
        int n = i * 4;
        f32x4 o;
#pragma unroll
        for (int k = 0; k < 4; k++)
            o[k] = (T[n + k][c] - mu_s[n + k]) * rs_s[n + k] * wv + bv;
        *(f32x4*)(out + ((size_t)b * 256 + c) * 4096 + n0 + n) = o;
    }
}

// ---------------------------------------------------------------------------
extern "C" void kernel_launch(void* const* d_in, const int* in_sizes, int n_in,
                              void* d_out, int out_size, void* d_ws, size_t ws_size,
                              hipStream_t stream) {
    const float* s3  = (const float*)d_in[0];
    const float* s4  = (const float*)d_in[1];
    const float* s5  = (const float*)d_in[2];
    const float* qw  = (const float*)d_in[3];
    const float* qb  = (const float*)d_in[4];
    const float* kw  = (const float*)d_in[5];
    const float* kb  = (const float*)d_in[6];
    const float* vw  = (const float*)d_in[7];
    const float* vb  = (const float*)d_in[8];
    const float* ow  = (const float*)d_in[9];
    const float* ob  = (const float*)d_in[10];
    const float* lnw = (const float*)d_in[11];
    const float* lnb = (const float*)d_in[12];
    float* out = (float*)d_out;
    char* ws = (char*)d_ws;

    // workspace layout (34.5 MB peak):
    bf16* Wb    = (bf16*)(ws);                          // 512 KB @ 0
    bf16* s3t   = (bf16*)(ws + (512ull << 10));         // 4 MB  @ 0.5 MB
    bf16* s45t  = (bf16*)(ws + (4608ull << 10));        // 3 MB  @ 4.5 MB
    bf16* Qb    = (bf16*)(ws + (7680ull << 10));        // 4 MB  @ 7.5 MB
    bf16* Kb    = Qb + (2ull * 8 * 4096 * 32);          // 3 MB  @ 11.5 MB
    f16*  Vtb   = (f16*)(Kb + (2ull * 8 * 3072 * 32));  // 3 MB  @ 14.5 MB
    f16*  Opart = (f16*)(ws + (17920ull << 10));        // 16 MB @ 17.5 MB (f16 [4sp][16bh][4096q][32d])
    float* Lsum = (float*)(ws + (34304ull << 10));      // 1 MB  @ 33.5 MB
    float* opre = (float*)(ws + (512ull << 10));        // 8 MB  @ 0.5 (s3t/s45t/Qb-head dead post-attn)

    const float qscale = 0.17677669529663688f * 1.4426950408889634f;  // 32^-0.5 * log2(e)

    k_prep<<<1152, 256, 0, stream>>>(qw, kw, vw, ow, Wb, s3, s4, s5, s3t, s45t);
    k_qkv<<<1280, 256, 0, stream>>>(Wb, s3t, s45t, qb, kb, vb, Qb, Kb, Vtb, qscale);
    k_attn<<<dim3(16, 16, 4), 256, 0, stream>>>(Qb, Kb, Vtb, Opart, Lsum);
    k_oproj<<<512, 256, 0, stream>>>(Wb + 196608, Opart, Lsum, ob, opre);
    k_ln<<<dim3(128, 2), 256, 0, stream>>>(opre, s3, lnw, lnb, out);
}